// Round 2
// baseline (203189.099 us; speedup 1.0000x reference)
//
#include <hip/hip_runtime.h>
#include <hip/hip_cooperative_groups.h>
#include <math.h>

namespace cg = cooperative_groups;

#define B 256
#define T 256
#define U 512
#define L 256
#define V 64
#define G4U 2048
#define BU (B * U)

#define BC 32   // batch rows per block tile
#define UC 16   // units per block tile

__device__ __forceinline__ float sigmoidf_(float x) { return 1.0f / (1.0f + expf(-x)); }

// Stage one 64-k tile (x rows + swizzled weights) to LDS and accumulate 4 gate dots.
// xsrc pre-offset to (row0, k0); wsrc pre-offset to (k0, 0) of a [*,4U] weight.
__device__ __forceinline__ void acc_tile(const float* __restrict__ xsrc, size_t xstride,
                                         const float* __restrict__ wsrc,
                                         float (*xs)[66], float (*ws)[64],
                                         int tid, int r, int uu, int uc,
                                         float& zi, float& zf, float& zg, float& zo)
{
    #pragma unroll
    for (int rep = 0; rep < 4; ++rep) {              // 32 rows x 64 k
        int li = rep * 512 + tid, rr = li >> 6, kk = li & 63;
        xs[rr][kk] = xsrc[(size_t)rr * xstride + kk];
    }
    #pragma unroll
    for (int rep = 0; rep < 8; ++rep) {              // 64 k x (16 units x 4 gates)
        int li = rep * 512 + tid, kk = li >> 6, j = li & 63;
        int g = j >> 4, uj = j & 15;
        ws[kk][uj * 4 + g] = wsrc[(size_t)kk * G4U + g * U + uc + uj];
    }
    __syncthreads();
    #pragma unroll
    for (int kk = 0; kk < 64; ++kk) {
        float a = xs[r][kk];                          // broadcast within 16-lane groups
        float4 w = *(const float4*)&ws[kk][uu * 4];   // 16 unique float4/wave, 2-way (free)
        zi = fmaf(a, w.x, zi); zf = fmaf(a, w.y, zf);
        zg = fmaf(a, w.z, zg); zo = fmaf(a, w.w, zo);
    }
    __syncthreads();
}

// One fused 3-layer LSTM stack (persistent cooperative kernel).
// Layer0: D=64 (x from [B,T,64]); layers 1,2: input = lower layer's current h.
// If projW != null: fused per-timestep projection U->V + argmax, written to out.
__global__ void __launch_bounds__(512, 1)
vae_stack(const float* __restrict__ x,
          const float* __restrict__ Wx0, const float* __restrict__ Wh0,
          const float* __restrict__ b0,  const float* __restrict__ pb0,
          const float* __restrict__ Wx1, const float* __restrict__ Wh1,
          const float* __restrict__ b1,
          const float* __restrict__ Wx2, const float* __restrict__ Wh2,
          const float* __restrict__ b2,
          float* __restrict__ hb,            // 6*B*U floats (3 layers x 2 buffers)
          const float* __restrict__ projW, const float* __restrict__ projB,
          float* __restrict__ out)
{
    cg::grid_group grid = cg::this_grid();
    __shared__ float xs[BC][66];
    __shared__ float ws[64][64];

    const int tid = threadIdx.x;
    const int bg = blockIdx.x >> 5, ug = blockIdx.x & 31;
    const int b0r = bg * BC, uc = ug * UC;
    const int r = tid >> 4, uu = tid & 15;
    const int ucol = uc + uu;
    const size_t myi = (size_t)(b0r + r) * U + ucol;

    float* h0 = hb;
    float* h1 = hb + 2 * (size_t)BU;
    float* h2 = hb + 4 * (size_t)BU;
    h0[myi] = 0.f; h1[myi] = 0.f; h2[myi] = 0.f;   // zero buffer 0 of each layer
    float c0 = 0.f, c1 = 0.f, c2 = 0.f;

    // bias preload (fixed per thread)
    float bi0, bf0, bg0, bo0;
    if (pb0) {  // decoder layer0: per-batch bias = dec_b0 + latent @ Wx0[0:L]
        const float* p = pb0 + (size_t)(b0r + r) * G4U;
        bi0 = p[ucol]; bf0 = p[U + ucol]; bg0 = p[2 * U + ucol]; bo0 = p[3 * U + ucol];
    } else {
        bi0 = b0[ucol]; bf0 = b0[U + ucol]; bg0 = b0[2 * U + ucol]; bo0 = b0[3 * U + ucol];
    }
    const float bi1 = b1[ucol], bf1 = b1[U + ucol], bg1 = b1[2 * U + ucol], bo1 = b1[3 * U + ucol];
    const float bi2 = b2[ucol], bf2 = b2[U + ucol], bg2 = b2[2 * U + ucol], bo2 = b2[3 * U + ucol];

    grid.sync();

    for (int t = 0; t < T; ++t) {
        const int rd = t & 1, wr = rd ^ 1;
        // ---------- layer 0 (1 x-tile + 8 recurrent tiles) ----------
        float zi = bi0, zf = bf0, zg = bg0, zo = bo0;
        acc_tile(x + (size_t)b0r * T * V + (size_t)t * V, (size_t)T * V, Wx0,
                 xs, ws, tid, r, uu, uc, zi, zf, zg, zo);
        {
            const float* h0r = h0 + (size_t)rd * BU + (size_t)b0r * U;
            for (int kt = 0; kt < 8; ++kt)
                acc_tile(h0r + kt * 64, U, Wh0 + (size_t)kt * 64 * G4U,
                         xs, ws, tid, r, uu, uc, zi, zf, zg, zo);
        }
        {
            float ig = sigmoidf_(zi), fg = sigmoidf_(zf), gg = tanhf(zg), og = sigmoidf_(zo);
            c0 = fg * c0 + ig * gg;
            h0[(size_t)wr * BU + myi] = og * tanhf(c0);
        }
        __threadfence();
        grid.sync();
        // ---------- layer 1 (8 x-tiles from h0 current + 8 recurrent) ----------
        zi = bi1; zf = bf1; zg = bg1; zo = bo1;
        {
            const float* xin = h0 + (size_t)wr * BU + (size_t)b0r * U;
            for (int kt = 0; kt < 8; ++kt)
                acc_tile(xin + kt * 64, U, Wx1 + (size_t)kt * 64 * G4U,
                         xs, ws, tid, r, uu, uc, zi, zf, zg, zo);
            const float* h1r = h1 + (size_t)rd * BU + (size_t)b0r * U;
            for (int kt = 0; kt < 8; ++kt)
                acc_tile(h1r + kt * 64, U, Wh1 + (size_t)kt * 64 * G4U,
                         xs, ws, tid, r, uu, uc, zi, zf, zg, zo);
        }
        {
            float ig = sigmoidf_(zi), fg = sigmoidf_(zf), gg = tanhf(zg), og = sigmoidf_(zo);
            c1 = fg * c1 + ig * gg;
            h1[(size_t)wr * BU + myi] = og * tanhf(c1);
        }
        __threadfence();
        grid.sync();
        // ---------- layer 2 ----------
        zi = bi2; zf = bf2; zg = bg2; zo = bo2;
        {
            const float* xin = h1 + (size_t)wr * BU + (size_t)b0r * U;
            for (int kt = 0; kt < 8; ++kt)
                acc_tile(xin + kt * 64, U, Wx2 + (size_t)kt * 64 * G4U,
                         xs, ws, tid, r, uu, uc, zi, zf, zg, zo);
            const float* h2r = h2 + (size_t)rd * BU + (size_t)b0r * U;
            for (int kt = 0; kt < 8; ++kt)
                acc_tile(h2r + kt * 64, U, Wh2 + (size_t)kt * 64 * G4U,
                         xs, ws, tid, r, uu, uc, zi, zf, zg, zo);
        }
        {
            float ig = sigmoidf_(zi), fg = sigmoidf_(zf), gg = tanhf(zg), og = sigmoidf_(zo);
            c2 = fg * c2 + ig * gg;
            h2[(size_t)wr * BU + myi] = og * tanhf(c2);
        }
        __threadfence();
        grid.sync();
        // ---------- fused projection + argmax (decoder only) ----------
        if (projW) {
            const float* hrow = h2 + (size_t)wr * BU + (size_t)blockIdx.x * U;  // block = batch row
            int v = tid & 63, part = tid >> 6;               // 8 k-parts x 64 vocab
            float ps = 0.f;
            const float* hp = hrow + part * 64;
            const float* wp = projW + (size_t)part * 64 * V + v;
            #pragma unroll
            for (int k = 0; k < 64; ++k) ps = fmaf(hp[k], wp[(size_t)k * V], ps);
            ws[part][v] = ps;
            __syncthreads();
            if (tid < 64) {                                   // wave 0
                float acc = projB[v];
                #pragma unroll
                for (int p = 0; p < 8; ++p) acc += ws[p][v];
                out[(size_t)B * T + ((size_t)blockIdx.x * T + t) * V + v] = acc;
                float best = acc; int bidx = v;
                #pragma unroll
                for (int off = 32; off; off >>= 1) {
                    float ov = __shfl_xor(best, off, 64);
                    int   oi = __shfl_xor(bidx, off, 64);
                    if (ov > best || (ov == best && oi < bidx)) { best = ov; bidx = oi; }
                }
                if (v == 0) out[(size_t)blockIdx.x * T + t] = (float)bidx;
            }
            __syncthreads();   // protect ws before next timestep's staging
        }
    }
}

__global__ void embed_k(const int* __restrict__ tok, const float* __restrict__ emb,
                        float* __restrict__ x)
{
    int idx = blockIdx.x * 256 + threadIdx.x;  // over B*T*16
    int pos = idx >> 4, c = idx & 15;
    int tkn = tok[pos];
    float4 v = ((const float4*)(emb + (size_t)tkn * V))[c];
    ((float4*)x)[(size_t)pos * 16 + c] = v;
}

// latent[b,l] = (h@wm+bm) + exp((h@ws+bs)/2)*eps ; h = hfin[b,:] (encoder final h2)
__global__ void latent_k(const float* __restrict__ hfin, const float* __restrict__ eps,
                         const float* __restrict__ wm, const float* __restrict__ bm,
                         const float* __restrict__ wsig, const float* __restrict__ bs,
                         float* __restrict__ latent)
{
    __shared__ float hrow[U];
    int b = blockIdx.x, l = threadIdx.x;
    hrow[l] = hfin[(size_t)b * U + l];
    hrow[l + 256] = hfin[(size_t)b * U + l + 256];
    __syncthreads();
    float am = bm[l], as = bs[l];
    for (int k = 0; k < U; ++k) {
        float h = hrow[k];
        am = fmaf(h, wm[(size_t)k * L + l], am);
        as = fmaf(h, wsig[(size_t)k * L + l], as);
    }
    latent[(size_t)b * L + l] = am + expf(as * 0.5f) * eps[(size_t)b * L + l];
}

// xc[b,:] = dec_b0 + latent[b,:] @ dec_Wx0[0:L,:]
__global__ void xc_k(const float* __restrict__ latent, const float* __restrict__ Wx0,
                     const float* __restrict__ b0v, float* __restrict__ xc)
{
    __shared__ float lat[L];
    int b = blockIdx.x >> 3;
    int col = (blockIdx.x & 7) * 256 + threadIdx.x;
    lat[threadIdx.x] = latent[(size_t)b * L + threadIdx.x];
    __syncthreads();
    float acc = b0v[col];
    for (int k = 0; k < L; ++k) acc = fmaf(lat[k], Wx0[(size_t)k * G4U + col], acc);
    xc[(size_t)b * G4U + col] = acc;
}

__global__ void sentinel_k(float* __restrict__ out, float val)
{
    out[threadIdx.x] = val;
}

extern "C" void kernel_launch(void* const* d_in, const int* in_sizes, int n_in,
                              void* d_out, int out_size, void* d_ws, size_t ws_size,
                              hipStream_t stream)
{
    const int*   tokens   = (const int*)  d_in[0];
    const float* eps      = (const float*)d_in[1];
    const float* emb      = (const float*)d_in[2];
    const float* enc_Wx0  = (const float*)d_in[3];
    const float* enc_Wh0  = (const float*)d_in[4];
    const float* enc_b0   = (const float*)d_in[5];
    const float* enc_Wx12 = (const float*)d_in[6];
    const float* enc_Wh12 = (const float*)d_in[7];
    const float* enc_b12  = (const float*)d_in[8];
    const float* w_mean   = (const float*)d_in[9];
    const float* b_mean   = (const float*)d_in[10];
    const float* w_sigma  = (const float*)d_in[11];
    const float* b_sigma  = (const float*)d_in[12];
    const float* dec_Wx0  = (const float*)d_in[13];
    const float* dec_Wh0  = (const float*)d_in[14];
    const float* dec_b0   = (const float*)d_in[15];
    const float* dec_Wx12 = (const float*)d_in[16];
    const float* dec_Wh12 = (const float*)d_in[17];
    const float* dec_b12  = (const float*)d_in[18];
    const float* dec_W    = (const float*)d_in[19];
    const float* dec_b    = (const float*)d_in[20];
    float* out = (float*)d_out;

    float* wsf   = (float*)d_ws;
    float* x_emb = wsf;                               // B*T*V   = 4,194,304 f
    float* hb    = x_emb + (size_t)B * T * V;         // 6*B*U   =   786,432 f
    float* lat   = hb + 6 * (size_t)BU;               // B*L     =    65,536 f
    float* xc    = lat + (size_t)B * L;               // B*4U    =   524,288 f
    size_t need  = ((size_t)B * T * V + 6 * (size_t)BU + (size_t)B * L +
                    (size_t)B * G4U) * sizeof(float);
    if (ws_size < need) {   // distinguishable failure: absmax ~1e6
        sentinel_k<<<dim3(1), dim3(64), 0, stream>>>(out, -1.0e6f);
        return;
    }

    embed_k<<<dim3(B * T * 16 / 256), dim3(256), 0, stream>>>(tokens, emb, x_emb);

    const float* nullf = nullptr;
    auto coop = [&](const float* x, const float* Wx0_, const float* Wh0_,
                    const float* b0_, const float* pb0_,
                    const float* Wx1_, const float* Wh1_, const float* b1_,
                    const float* Wx2_, const float* Wh2_, const float* b2_,
                    const float* pW, const float* pB) -> hipError_t {
        void* args[] = { (void*)&x, (void*)&Wx0_, (void*)&Wh0_, (void*)&b0_, (void*)&pb0_,
                         (void*)&Wx1_, (void*)&Wh1_, (void*)&b1_,
                         (void*)&Wx2_, (void*)&Wh2_, (void*)&b2_,
                         (void*)&hb, (void*)&pW, (void*)&pB, (void*)&out };
        return hipLaunchCooperativeKernel((void*)vae_stack, dim3(256), dim3(512),
                                          args, 0, stream);
    };

    // encoder
    hipError_t e1 = coop(x_emb, enc_Wx0, enc_Wh0, enc_b0, nullf,
                         enc_Wx12, enc_Wh12, enc_b12,
                         enc_Wx12 + (size_t)U * G4U, enc_Wh12 + (size_t)U * G4U,
                         enc_b12 + G4U, nullf, nullf);
    // latent head reads encoder final h2 (written to buffer 0 at t=T-1)
    const float* hfin = hb + 4 * (size_t)BU;
    latent_k<<<dim3(B), dim3(256), 0, stream>>>(hfin, eps, w_mean, b_mean,
                                                w_sigma, b_sigma, lat);
    xc_k<<<dim3(2048), dim3(256), 0, stream>>>(lat, dec_Wx0, dec_b0, xc);
    // decoder (layer0 x-part only, latent part folded into xc) + fused projection
    hipError_t e2 = coop(x_emb, dec_Wx0 + (size_t)L * G4U, dec_Wh0, nullf, xc,
                         dec_Wx12, dec_Wh12, dec_b12,
                         dec_Wx12 + (size_t)U * G4U, dec_Wh12 + (size_t)U * G4U,
                         dec_b12 + G4U, dec_W, dec_b);
    if (e1 != hipSuccess || e2 != hipSuccess) {  // distinguishable: absmax ~2e6
        sentinel_k<<<dim3(1), dim3(64), 0, stream>>>(out, -2.0e6f);
    }
}

// Round 5
// 65545.496 us; speedup vs baseline: 3.1000x; 3.1000x over previous
//
#include <hip/hip_runtime.h>
#include <hip/hip_cooperative_groups.h>
#include <math.h>

namespace cg = cooperative_groups;

#define B 256
#define T 256
#define U 512
#define L 256
#define V 64
#define G4U 2048
#define BU (B * U)

// wlo region offsets (ushort elements)
#define WLO_R1 1179648          // 64 * 576 * 32
#define WLO_R2 3276800          // WLO_R1 + 64*1024*32
#define WLO_TOTAL 5373952       // WLO_R2 + 64*1024*32

typedef __attribute__((ext_vector_type(8))) short bf16x8;
typedef __attribute__((ext_vector_type(16))) float f32x16;

__device__ __forceinline__ unsigned short bf16_hi(float x) {
    union { float f; unsigned int u; } c; c.f = x;
    unsigned int r = c.u + 0x7fffu + ((c.u >> 16) & 1u);   // RNE
    return (unsigned short)(r >> 16);
}
__device__ __forceinline__ float bf16_f(unsigned short h) {
    union { unsigned int u; float f; } c; c.u = ((unsigned int)h) << 16;
    return c.f;
}

// Fused 3-layer LSTM stack, diagonal-pipelined, split-bf16 MFMA.
// Blocks 0-63: layer0; 64-127: layer1; 128-191: layer2; 192-255: projection.
// LDS: 64KB static (weight hi-plane). Weight lo-plane prepacked in global.
__global__ void __launch_bounds__(512, 1)
vae_stack(const unsigned short* __restrict__ xhi, const unsigned short* __restrict__ xlo,
          const float* __restrict__ Wx0, const float* __restrict__ Wh0,
          const float* __restrict__ Wx1, const float* __restrict__ Wh1,
          const float* __restrict__ Wx2, const float* __restrict__ Wh2,
          const unsigned short* __restrict__ wlo,
          const float* __restrict__ cb_base, const float* __restrict__ rb0,
          unsigned short* __restrict__ h,
          const float* __restrict__ projW, const float* __restrict__ projB,
          float* __restrict__ out, int nphase)
{
    cg::grid_group grid = cg::this_grid();
    __shared__ __align__(16) char smem[65536];
    const int tid = threadIdx.x;
    const int bid = blockIdx.x;
    const int role = bid >> 6;
    const int ug = bid & 63;
    const int lane = tid & 63;
    const int wv = tid >> 6;        // wave id
    const int m0 = wv * 32;

    // zero all h buffers (12*BU ushorts = 786432 uints), one slice per thread
    {
        unsigned int* hz = (unsigned int*)h;
        int gid = bid * 512 + tid;
        #pragma unroll
        for (int i = 0; i < 6; ++i) hz[gid + i * 131072] = 0u;
    }

    auto HP = [&](int layer, int buf, int pl) -> unsigned short* {
        return h + (((size_t)(layer * 2 + buf) * 2 + pl) * (size_t)BU);
    };

    if (role < 3) {
        const int K  = (role == 0) ? 576 : 1024;
        const int Dx = (role == 0) ? 64 : 512;
        unsigned short* Whi = (unsigned short*)smem;    // [K/8][32][8], <=64KB

        // one-time weight hi-plane stage (col slot n = u*4+g; col = g*512+ug*8+u)
        const float* WxL = (role == 0) ? Wx0 : ((role == 1) ? Wx1 : Wx2);
        const float* WhL = (role == 0) ? Wh0 : ((role == 1) ? Wh1 : Wh2);
        for (int idx = tid; idx < K * 32; idx += 512) {
            int k = idx >> 5, n = idx & 31, u = n >> 2, g = n & 3;
            int col = g * 512 + ug * 8 + u;
            float w = (k < Dx) ? WxL[(size_t)k * G4U + col]
                               : WhL[(size_t)(k - Dx) * G4U + col];
            Whi[((k >> 3) * 32 + n) * 8 + (k & 7)] = bf16_hi(w);
        }
        const unsigned short* wloB =
            (role == 0) ? wlo + (size_t)ug * (576 * 32)
                        : wlo + WLO_R1 + (size_t)(role - 1) * 2097152 + (size_t)ug * 32768;

        const bool userb = (role == 0) && (rb0 != nullptr);
        const float colbias = userb ? 0.0f
                            : cb_base[role * 2048 + ug * 32 + (lane & 31)];
        float cst[16];
        #pragma unroll
        for (int i = 0; i < 16; ++i) cst[i] = 0.0f;

        const int arow = m0 + (lane & 31);      // A row (batch)
        const int kh8  = (lane >> 5) * 8;       // k-half offset in 16-chunk

        __syncthreads();
        __threadfence();
        grid.sync();

        // one 16-k chunk: global A frags (hi/lo), LDS B-hi + global B-lo, 3 MFMAs
        auto step = [&](const unsigned short* ah, const unsigned short* al,
                        int c, f32x16& acc) {
            bf16x8 ahi = *(const bf16x8*)ah;
            bf16x8 alo = *(const bf16x8*)al;
            const int bo = ((c * 2 + (lane >> 5)) * 32 + (lane & 31)) * 8;
            bf16x8 bhi = *(const bf16x8*)(Whi + bo);
            bf16x8 blo = *(const bf16x8*)(wloB + bo);
            acc = __builtin_amdgcn_mfma_f32_32x32x16_bf16(ahi, bhi, acc, 0, 0, 0);
            acc = __builtin_amdgcn_mfma_f32_32x32x16_bf16(ahi, blo, acc, 0, 0, 0);
            acc = __builtin_amdgcn_mfma_f32_32x32x16_bf16(alo, bhi, acc, 0, 0, 0);
        };

        for (int p = 0; p < nphase; ++p) {
            const int t = p - role;
            if (t >= 0 && t < T) {
                f32x16 acc;
                #pragma unroll
                for (int i = 0; i < 16; ++i) acc[i] = 0.0f;

                if (role == 0) {
                    const size_t xo = ((size_t)arow * T + t) * V + kh8;
                    #pragma unroll
                    for (int ks = 0; ks < 4; ++ks)
                        step(xhi + xo + ks * 16, xlo + xo + ks * 16, ks, acc);
                    const unsigned short* hh = HP(0, (t + 1) & 1, 0) + (size_t)arow * U + kh8;
                    const unsigned short* hl = HP(0, (t + 1) & 1, 1) + (size_t)arow * U + kh8;
                    #pragma unroll 4
                    for (int ks = 0; ks < 32; ++ks)
                        step(hh + ks * 16, hl + ks * 16, 4 + ks, acc);
                } else {
                    const unsigned short* xh = HP(role - 1, t & 1, 0) + (size_t)arow * U + kh8;
                    const unsigned short* xl = HP(role - 1, t & 1, 1) + (size_t)arow * U + kh8;
                    #pragma unroll 4
                    for (int ks = 0; ks < 32; ++ks)
                        step(xh + ks * 16, xl + ks * 16, ks, acc);
                    const unsigned short* hh = HP(role, (t + 1) & 1, 0) + (size_t)arow * U + kh8;
                    const unsigned short* hl = HP(role, (t + 1) & 1, 1) + (size_t)arow * U + kh8;
                    #pragma unroll 4
                    for (int ks = 0; ks < 32; ++ks)
                        step(hh + ks * 16, hl + ks * 16, 32 + ks, acc);
                }

                // pointwise: C layout col=lane&31, row=(r&3)+8*(r>>2)+4*(lane>>5)
                const int n = lane & 31, g = n & 3, u8 = n >> 2, hi5 = lane >> 5;
                unsigned short* hwh = HP(role, t & 1, 0);
                unsigned short* hwl = HP(role, t & 1, 1);
                const int gu = ug * 8 + u8;
                const bool g1 = (g & 1), g2 = (g & 2);
                #pragma unroll
                for (int r = 0; r < 16; ++r) {
                    int grow = m0 + (r & 3) + 8 * (r >> 2) + 4 * hi5;
                    float z = acc[r] + colbias;
                    if (userb) z += rb0[(size_t)grow * G4U + ug * 32 + n];
                    float zb = __shfl_xor(z, 1, 64);
                    float zc = __shfl_xor(z, 2, 64);
                    float zd = __shfl_xor(z, 3, 64);
                    float t01 = g1 ? zb : z,  t23 = g1 ? zd : zc;
                    float u01 = g1 ? z  : zb, u23 = g1 ? zc : zd;
                    float zi = g2 ? t23 : t01;
                    float zf = g2 ? u23 : u01;
                    float zG = g2 ? t01 : t23;
                    float zo = g2 ? u01 : u23;
                    float ig = 1.0f / (1.0f + expf(-zi));
                    float fg = 1.0f / (1.0f + expf(-zf));
                    float gg = tanhf(zG);
                    float og = 1.0f / (1.0f + expf(-zo));
                    cst[r] = fg * cst[r] + ig * gg;
                    float hv = og * tanhf(cst[r]);
                    if (g == 0) {
                        unsigned short hh2 = bf16_hi(hv);
                        unsigned short hl2 = bf16_hi(hv - bf16_f(hh2));
                        hwh[(size_t)grow * U + gu] = hh2;
                        hwl[(size_t)grow * U + gu] = hl2;
                    }
                }
            }
            __threadfence();
            grid.sync();
        }
    } else {
        // ---------------- projection + argmax (decoder) / idle (encoder) ----
        float* hrow  = (float*)smem;            // [4][512]
        float* parts = (float*)(smem + 8192);   // [256]
        const int b0p = ug * 4;
        const float pbv = projW ? projB[lane] : 0.0f;
        const int r = wv & 3, kp = wv >> 2, v = lane;
        __threadfence();
        grid.sync();
        for (int p = 0; p < nphase; ++p) {
            const int tp = p - 3;
            if (projW && tp >= 0 && tp < T) {
                {   // stage 4 h2 rows (hi+lo recon) into LDS
                    int rr = tid >> 7, kq = (tid & 127) * 4;
                    const unsigned short* h2h = HP(2, tp & 1, 0);
                    const unsigned short* h2l = HP(2, tp & 1, 1);
                    size_t off = (size_t)(b0p + rr) * U + kq;
                    ushort4 vh = *(const ushort4*)(h2h + off);
                    ushort4 vl = *(const ushort4*)(h2l + off);
                    float4 f;
                    f.x = bf16_f(vh.x) + bf16_f(vl.x);
                    f.y = bf16_f(vh.y) + bf16_f(vl.y);
                    f.z = bf16_f(vh.z) + bf16_f(vl.z);
                    f.w = bf16_f(vh.w) + bf16_f(vl.w);
                    *(float4*)(hrow + rr * 512 + kq) = f;
                }
                __syncthreads();
                // wave w: r=w&3 (batch row), kp=w>>2 (k half); lane = vocab v.
                // W reads coalesced (dec_W is [k][v]); hrow broadcast from LDS.
                float acc = 0.0f;
                const float* wp = projW + (size_t)(kp * 256) * V + v;
                const float* hp = hrow + r * 512 + kp * 256;
                #pragma unroll 8
                for (int k = 0; k < 256; ++k)
                    acc = fmaf(wp[(size_t)k * V], hp[k], acc);
                if (kp == 1) parts[r * 64 + v] = acc;
                __syncthreads();
                if (kp == 0) {
                    float logit = acc + parts[r * 64 + v] + pbv;
                    int grow = b0p + r;
                    out[(size_t)B * T + ((size_t)grow * T + tp) * V + v] = logit;
                    float best = logit; int bi = v;
                    #pragma unroll
                    for (int off = 32; off; off >>= 1) {
                        float ov = __shfl_xor(best, off, 64);
                        int oi  = __shfl_xor(bi, off, 64);
                        if (ov > best || (ov == best && oi < bi)) { best = ov; bi = oi; }
                    }
                    if (v == 0) out[(size_t)grow * T + tp] = (float)bi;
                }
            }
            __threadfence();
            grid.sync();
        }
    }
}

// ---------------- prep kernels ----------------
__global__ void embed_split_k(const int* __restrict__ tok, const float* __restrict__ emb,
                              unsigned short* __restrict__ xh, unsigned short* __restrict__ xl)
{
    int idx = blockIdx.x * 256 + threadIdx.x;   // B*T*16 quads
    int pos = idx >> 4, c = (idx & 15) * 4;
    int tk = tok[pos];
    float4 v = *(const float4*)(emb + (size_t)tk * V + c);
    ushort4 h, l;
    h.x = bf16_hi(v.x); l.x = bf16_hi(v.x - bf16_f(h.x));
    h.y = bf16_hi(v.y); l.y = bf16_hi(v.y - bf16_f(h.y));
    h.z = bf16_hi(v.z); l.z = bf16_hi(v.z - bf16_f(h.z));
    h.w = bf16_hi(v.w); l.w = bf16_hi(v.w - bf16_f(h.w));
    *(ushort4*)(xh + (size_t)pos * V + c) = h;
    *(ushort4*)(xl + (size_t)pos * V + c) = l;
}

// weight lo-plane prepack, fragment order (per block ug: [K/8][32][8])
__global__ void wlo_k(const float* __restrict__ Wx, const float* __restrict__ Wh,
                      unsigned short* __restrict__ dst, int K, int Dx)
{
    int idx = blockIdx.x * 256 + threadIdx.x;   // 64 * K * 32
    int ug = idx / (K * 32);
    int rem = idx - ug * (K * 32);
    int k = rem >> 5, n = rem & 31, u = n >> 2, g = n & 3;
    int col = g * 512 + ug * 8 + u;
    float w = (k < Dx) ? Wx[(size_t)k * G4U + col] : Wh[(size_t)(k - Dx) * G4U + col];
    unsigned short hi = bf16_hi(w);
    dst[(size_t)ug * (K * 32) + ((k >> 3) * 32 + n) * 8 + (k & 7)] = bf16_hi(w - bf16_f(hi));
}

__global__ void latent_k(const unsigned short* __restrict__ h2h,
                         const unsigned short* __restrict__ h2l,
                         const float* __restrict__ eps,
                         const float* __restrict__ wm, const float* __restrict__ bm,
                         const float* __restrict__ wsig, const float* __restrict__ bs,
                         float* __restrict__ lat)
{
    __shared__ float hr[U];
    int b = blockIdx.x, l = threadIdx.x;
    hr[l]       = bf16_f(h2h[(size_t)b * U + l])       + bf16_f(h2l[(size_t)b * U + l]);
    hr[l + 256] = bf16_f(h2h[(size_t)b * U + l + 256]) + bf16_f(h2l[(size_t)b * U + l + 256]);
    __syncthreads();
    float am = bm[l], as = bs[l];
    for (int k = 0; k < U; ++k) {
        float h = hr[k];
        am = fmaf(h, wm[(size_t)k * L + l], am);
        as = fmaf(h, wsig[(size_t)k * L + l], as);
    }
    lat[(size_t)b * L + l] = am + expf(as * 0.5f) * eps[(size_t)b * L + l];
}

// xcr[b][ugi*32+u*4+g] = dec_b0 + latent @ dec_Wx0[0:L]  (col oc = g*512+ugi*8+u)
__global__ void xcr_k(const float* __restrict__ lat, const float* __restrict__ Wx0,
                      const float* __restrict__ b0v, float* __restrict__ xcr)
{
    __shared__ float lr[L];
    int b = blockIdx.x >> 3;
    int oc = (blockIdx.x & 7) * 256 + threadIdx.x;
    lr[threadIdx.x] = lat[(size_t)b * L + threadIdx.x];
    __syncthreads();
    float acc = b0v[oc];
    for (int k = 0; k < L; ++k) acc = fmaf(lr[k], Wx0[(size_t)k * G4U + oc], acc);
    int g = oc >> 9, rest = oc & 511, ugi = rest >> 3, u = rest & 7;
    xcr[(size_t)b * G4U + ugi * 32 + u * 4 + g] = acc;
}

__global__ void biasref_k(const float* s0, const float* s1, const float* s2,
                          const float* s3, const float* s4, float* __restrict__ ebr)
{
    int idx = blockIdx.x * 256 + threadIdx.x;   // 5*2048
    int which = idx >> 11, oc = idx & 2047;
    const float* s = which == 0 ? s0 : which == 1 ? s1 : which == 2 ? s2
                   : which == 3 ? s3 : s4;
    int g = oc >> 9, rest = oc & 511, ugi = rest >> 3, u = rest & 7;
    ebr[which * 2048 + ugi * 32 + u * 4 + g] = s[oc];
}

__global__ void sentinel_k(float* __restrict__ out, float val) { out[threadIdx.x] = val; }

extern "C" void kernel_launch(void* const* d_in, const int* in_sizes, int n_in,
                              void* d_out, int out_size, void* d_ws, size_t ws_size,
                              hipStream_t stream)
{
    const int*   tokens   = (const int*)  d_in[0];
    const float* eps      = (const float*)d_in[1];
    const float* emb      = (const float*)d_in[2];
    const float* enc_Wx0  = (const float*)d_in[3];
    const float* enc_Wh0  = (const float*)d_in[4];
    const float* enc_b0   = (const float*)d_in[5];
    const float* enc_Wx12 = (const float*)d_in[6];
    const float* enc_Wh12 = (const float*)d_in[7];
    const float* enc_b12  = (const float*)d_in[8];
    const float* w_mean   = (const float*)d_in[9];
    const float* b_mean   = (const float*)d_in[10];
    const float* w_sigma  = (const float*)d_in[11];
    const float* b_sigma  = (const float*)d_in[12];
    const float* dec_Wx0  = (const float*)d_in[13];
    const float* dec_Wh0  = (const float*)d_in[14];
    const float* dec_b0   = (const float*)d_in[15];
    const float* dec_Wx12 = (const float*)d_in[16];
    const float* dec_Wh12 = (const float*)d_in[17];
    const float* dec_b12  = (const float*)d_in[18];
    const float* dec_W    = (const float*)d_in[19];
    const float* dec_b    = (const float*)d_in[20];
    float* out = (float*)d_out;

    // workspace carve-up (all 16B aligned)
    unsigned short* xhi = (unsigned short*)d_ws;                  // B*T*V us
    unsigned short* xlo = xhi + (size_t)B * T * V;                // B*T*V us
    unsigned short* h   = xlo + (size_t)B * T * V;                // 12*BU us
    unsigned short* wlo = h + 12 * (size_t)BU;                    // WLO_TOTAL us
    float* lat = (float*)(wlo + WLO_TOTAL);                       // B*L
    float* xcr = lat + (size_t)B * L;                             // B*2048
    float* ebr = xcr + (size_t)B * G4U;                           // 5*2048
    size_t need = (size_t)((char*)(ebr + 5 * G4U) - (char*)d_ws);
    if (ws_size < need) {
        sentinel_k<<<dim3(1), dim3(64), 0, stream>>>(out, -1.0e6f);
        return;
    }

    const size_t UG = (size_t)U * G4U;

    embed_split_k<<<dim3(B * T * 16 / 256), dim3(256), 0, stream>>>(tokens, emb, xhi, xlo);
    biasref_k<<<dim3(40), dim3(256), 0, stream>>>(enc_b0, enc_b12, enc_b12 + G4U,
                                                  dec_b12, dec_b12 + G4U, ebr);

    auto coop = [&](const float* Wx0_, const float* Wh0_,
                    const float* Wx1_, const float* Wh1_,
                    const float* Wx2_, const float* Wh2_,
                    const float* cbb, const float* rb,
                    const float* pW, const float* pB, int np) -> hipError_t {
        const unsigned short* a_xhi = xhi;
        const unsigned short* a_xlo = xlo;
        const unsigned short* a_wlo = wlo;
        unsigned short* a_h = h;
        float* a_out = out;
        void* args[] = { (void*)&a_xhi, (void*)&a_xlo,
                         (void*)&Wx0_, (void*)&Wh0_, (void*)&Wx1_, (void*)&Wh1_,
                         (void*)&Wx2_, (void*)&Wh2_, (void*)&a_wlo,
                         (void*)&cbb, (void*)&rb, (void*)&a_h,
                         (void*)&pW, (void*)&pB, (void*)&a_out, (void*)&np };
        return hipLaunchCooperativeKernel((void*)vae_stack, dim3(256), dim3(512),
                                          args, 0, stream);
    };

    // ---------------- encoder ----------------
    wlo_k<<<dim3(4608), dim3(256), 0, stream>>>(enc_Wx0, enc_Wh0, wlo, 576, 64);
    wlo_k<<<dim3(8192), dim3(256), 0, stream>>>(enc_Wx12, enc_Wh12, wlo + WLO_R1, 1024, 512);
    wlo_k<<<dim3(8192), dim3(256), 0, stream>>>(enc_Wx12 + UG, enc_Wh12 + UG,
                                                wlo + WLO_R2, 1024, 512);
    hipError_t e1 = coop(enc_Wx0, enc_Wh0, enc_Wx12, enc_Wh12,
                         enc_Wx12 + UG, enc_Wh12 + UG,
                         ebr, nullptr, nullptr, nullptr, T + 2);

    // latent head reads encoder h2[t=255] (buf 1): planes at 10*BU, 11*BU
    latent_k<<<dim3(B), dim3(256), 0, stream>>>(h + 10 * (size_t)BU, h + 11 * (size_t)BU,
                                                eps, w_mean, b_mean, w_sigma, b_sigma, lat);
    xcr_k<<<dim3(2048), dim3(256), 0, stream>>>(lat, dec_Wx0, dec_b0, xcr);

    // ---------------- decoder ----------------
    wlo_k<<<dim3(4608), dim3(256), 0, stream>>>(dec_Wx0 + (size_t)L * G4U, dec_Wh0,
                                                wlo, 576, 64);
    wlo_k<<<dim3(8192), dim3(256), 0, stream>>>(dec_Wx12, dec_Wh12, wlo + WLO_R1, 1024, 512);
    wlo_k<<<dim3(8192), dim3(256), 0, stream>>>(dec_Wx12 + UG, dec_Wh12 + UG,
                                                wlo + WLO_R2, 1024, 512);
    hipError_t e2 = coop(dec_Wx0 + (size_t)L * G4U, dec_Wh0, dec_Wx12, dec_Wh12,
                         dec_Wx12 + UG, dec_Wh12 + UG,
                         ebr + 2 * G4U, xcr, dec_W, dec_b, T + 3);

    if (e1 != hipSuccess || e2 != hipSuccess) {
        sentinel_k<<<dim3(1), dim3(64), 0, stream>>>(out, -3.0e6f);
    }
}

// Round 6
// 62806.116 us; speedup vs baseline: 3.2352x; 1.0436x over previous
//
#include <hip/hip_runtime.h>
#include <hip/hip_cooperative_groups.h>
#include <math.h>

namespace cg = cooperative_groups;

#define B 256
#define T 256
#define U 512
#define L 256
#define V 64
#define G4U 2048
#define BU (B * U)
#define HBUF 262144   // ushorts per (layer,buf) interleaved h panel: 256 rows * 1024

// wlo region offsets (ushort elements)
#define WLO_R1 1179648          // 64 * 576 * 32
#define WLO_R2 3276800          // WLO_R1 + 64*1024*32
#define WLO_TOTAL 5373952       // WLO_R2 + 64*1024*32

typedef __attribute__((ext_vector_type(8))) short bf16x8;
typedef __attribute__((ext_vector_type(16))) float f32x16;

__device__ __forceinline__ unsigned short bf16_hi(float x) {
    union { float f; unsigned int u; } c; c.f = x;
    unsigned int r = c.u + 0x7fffu + ((c.u >> 16) & 1u);   // RNE
    return (unsigned short)(r >> 16);
}
__device__ __forceinline__ float bf16_f(unsigned short h) {
    union { unsigned int u; float f; } c; c.u = ((unsigned int)h) << 16;
    return c.f;
}

// Software-pipelined GEMM sub-loop over NCH 16-k chunks (NCH % 4 == 0).
// abase: A panel at this lane's row, first chunk (interleaved [chunk][16hi|16lo]).
// bhiB/bloB: B fragment bases (LDS hi / global lo), chunk stride 512 ushorts.
// Batch b+1's 12 loads issue before batch b's 12 MFMAs -> ~12 loads in flight.
template<int NCH>
__device__ __forceinline__ void gemm_sub(const unsigned short* __restrict__ abase,
                                         const unsigned short* __restrict__ bhiB,
                                         const unsigned short* __restrict__ bloB,
                                         int kh8, f32x16& acc)
{
    constexpr int NB = NCH / 4;
    bf16x8 ah[2][4], al[2][4], bl[2][4];
    #pragma unroll
    for (int i = 0; i < 4; ++i) {
        ah[0][i] = *(const bf16x8*)(abase + i * 32 + kh8);
        al[0][i] = *(const bf16x8*)(abase + i * 32 + 16 + kh8);
        bl[0][i] = *(const bf16x8*)(bloB + i * 512);
    }
    #pragma unroll
    for (int b = 0; b < NB; ++b) {
        const int cur = b & 1, nxt = cur ^ 1;
        if (b + 1 < NB) {
            #pragma unroll
            for (int i = 0; i < 4; ++i) {
                const int c = (b + 1) * 4 + i;
                ah[nxt][i] = *(const bf16x8*)(abase + c * 32 + kh8);
                al[nxt][i] = *(const bf16x8*)(abase + c * 32 + 16 + kh8);
                bl[nxt][i] = *(const bf16x8*)(bloB + c * 512);
            }
        }
        #pragma unroll
        for (int i = 0; i < 4; ++i) {
            const int c = b * 4 + i;
            bf16x8 bh = *(const bf16x8*)(bhiB + c * 512);
            acc = __builtin_amdgcn_mfma_f32_32x32x16_bf16(ah[cur][i], bh, acc, 0, 0, 0);
            acc = __builtin_amdgcn_mfma_f32_32x32x16_bf16(ah[cur][i], bl[cur][i], acc, 0, 0, 0);
            acc = __builtin_amdgcn_mfma_f32_32x32x16_bf16(al[cur][i], bh, acc, 0, 0, 0);
        }
    }
}

// Fused 3-layer LSTM stack, diagonal-pipelined, split-bf16 MFMA.
// Blocks 0-63: layer0; 64-127: layer1; 128-191: layer2; 192-255: projection.
// LDS: 64KB static (weight hi-plane). Weight lo-plane prepacked in global.
// x and h panels interleaved [row][chunk][16hi|16lo] -> 1 cache line/lane/chunk.
__global__ void __launch_bounds__(512, 1)
vae_stack(const unsigned short* __restrict__ xI,
          const float* __restrict__ Wx0, const float* __restrict__ Wh0,
          const float* __restrict__ Wx1, const float* __restrict__ Wh1,
          const float* __restrict__ Wx2, const float* __restrict__ Wh2,
          const unsigned short* __restrict__ wlo,
          const float* __restrict__ cb_base, const float* __restrict__ rb0,
          unsigned short* __restrict__ h,
          const float* __restrict__ projW, const float* __restrict__ projB,
          float* __restrict__ out, int nphase)
{
    cg::grid_group grid = cg::this_grid();
    __shared__ __align__(16) char smem[65536];
    const int tid = threadIdx.x;
    const int bid = blockIdx.x;
    const int role = bid >> 6;
    const int ug = bid & 63;
    const int lane = tid & 63;
    const int wv = tid >> 6;        // wave id
    const int m0 = wv * 32;

    // zero all h buffers (6 interleaved panels = 1.57M ushorts), 1 slice/thread
    {
        unsigned int* hz = (unsigned int*)h;
        int gid = bid * 512 + tid;
        #pragma unroll
        for (int i = 0; i < 6; ++i) hz[gid + i * 131072] = 0u;
    }

    auto HP = [&](int layer, int buf) -> unsigned short* {
        return h + (size_t)(layer * 2 + buf) * HBUF;
    };

    if (role < 3) {
        const int K  = (role == 0) ? 576 : 1024;
        const int Dx = (role == 0) ? 64 : 512;
        unsigned short* Whi = (unsigned short*)smem;    // [K/8][32][8], <=64KB

        // one-time weight hi-plane stage (col slot n = u*4+g; col = g*512+ug*8+u)
        const float* WxL = (role == 0) ? Wx0 : ((role == 1) ? Wx1 : Wx2);
        const float* WhL = (role == 0) ? Wh0 : ((role == 1) ? Wh1 : Wh2);
        for (int idx = tid; idx < K * 32; idx += 512) {
            int k = idx >> 5, n = idx & 31, u = n >> 2, g = n & 3;
            int col = g * 512 + ug * 8 + u;
            float w = (k < Dx) ? WxL[(size_t)k * G4U + col]
                               : WhL[(size_t)(k - Dx) * G4U + col];
            Whi[((k >> 3) * 32 + n) * 8 + (k & 7)] = bf16_hi(w);
        }
        const unsigned short* wloB =
            (role == 0) ? wlo + (size_t)ug * (576 * 32)
                        : wlo + WLO_R1 + (size_t)(role - 1) * 2097152 + (size_t)ug * 32768;

        const bool userb = (role == 0) && (rb0 != nullptr);
        const float colbias = userb ? 0.0f
                            : cb_base[role * 2048 + ug * 32 + (lane & 31)];
        float cst[16];
        #pragma unroll
        for (int i = 0; i < 16; ++i) cst[i] = 0.0f;

        const int arow = m0 + (lane & 31);      // A row (batch)
        const int kh8  = (lane >> 5) * 8;       // k-half offset in 16-chunk
        const int frg  = (lane >> 5) * 256 + (lane & 31) * 8;  // B frag offset

        __syncthreads();
        __threadfence();
        grid.sync();

        for (int p = 0; p < nphase; ++p) {
            const int t = p - role;
            if (t >= 0 && t < T) {
                const int wr = t & 1, rd = wr ^ 1;
                f32x16 acc;
                #pragma unroll
                for (int i = 0; i < 16; ++i) acc[i] = 0.0f;

                if (role == 0) {
                    gemm_sub<4>(xI + ((size_t)arow * T + t) * 128,
                                Whi + frg, wloB + frg, kh8, acc);
                    gemm_sub<32>(HP(0, rd) + (size_t)arow * 1024,
                                 Whi + 4 * 512 + frg, wloB + 4 * 512 + frg, kh8, acc);
                } else {
                    gemm_sub<32>(HP(role - 1, wr) + (size_t)arow * 1024,
                                 Whi + frg, wloB + frg, kh8, acc);
                    gemm_sub<32>(HP(role, rd) + (size_t)arow * 1024,
                                 Whi + 32 * 512 + frg, wloB + 32 * 512 + frg, kh8, acc);
                }

                // pointwise: C layout col=lane&31, row=(r&3)+8*(r>>2)+4*(lane>>5)
                const int n = lane & 31, g = n & 3, u8 = n >> 2, hi5 = lane >> 5;
                unsigned short* hw = HP(role, wr);
                const int gu = ug * 8 + u8;
                const int guo = (gu >> 4) * 32 + (gu & 15);   // interleaved offset
                const bool g1 = (g & 1), g2 = (g & 2);
                #pragma unroll
                for (int r = 0; r < 16; ++r) {
                    int grow = m0 + (r & 3) + 8 * (r >> 2) + 4 * hi5;
                    float z = acc[r] + colbias;
                    if (userb) z += rb0[(size_t)grow * G4U + ug * 32 + n];
                    float zb = __shfl_xor(z, 1, 64);
                    float zc = __shfl_xor(z, 2, 64);
                    float zd = __shfl_xor(z, 3, 64);
                    float t01 = g1 ? zb : z,  t23 = g1 ? zd : zc;
                    float u01 = g1 ? z  : zb, u23 = g1 ? zc : zd;
                    float zi = g2 ? t23 : t01;
                    float zf = g2 ? u23 : u01;
                    float zG = g2 ? t01 : t23;
                    float zo = g2 ? u01 : u23;
                    float ig = 1.0f / (1.0f + expf(-zi));
                    float fg = 1.0f / (1.0f + expf(-zf));
                    float gg = tanhf(zG);
                    float og = 1.0f / (1.0f + expf(-zo));
                    cst[r] = fg * cst[r] + ig * gg;
                    float hv = og * tanhf(cst[r]);
                    if (g == 0) {
                        unsigned short hh2 = bf16_hi(hv);
                        unsigned short hl2 = bf16_hi(hv - bf16_f(hh2));
                        size_t ho = (size_t)grow * 1024 + guo;
                        hw[ho] = hh2;
                        hw[ho + 16] = hl2;
                    }
                }
            }
            __threadfence();
            grid.sync();
        }
    } else {
        // ---------------- projection + argmax (decoder) / idle (encoder) ----
        float* hrow  = (float*)smem;            // [4][512]
        float* parts = (float*)(smem + 8192);   // [256]
        const int b0p = ug * 4;
        const float pbv = projW ? projB[lane] : 0.0f;
        const int r = wv & 3, kp = wv >> 2, v = lane;
        __threadfence();
        grid.sync();
        for (int p = 0; p < nphase; ++p) {
            const int tp = p - 3;
            if (projW && tp >= 0 && tp < T) {
                {   // stage 4 h2 rows (hi+lo recon) into LDS
                    int rr = tid >> 7, kq = (tid & 127) * 4;   // 4 units, same chunk
                    const unsigned short* hb2 = HP(2, tp & 1)
                        + (size_t)(b0p + rr) * 1024 + (kq >> 4) * 32 + (kq & 15);
                    ushort4 vh = *(const ushort4*)hb2;
                    ushort4 vl = *(const ushort4*)(hb2 + 16);
                    float4 f;
                    f.x = bf16_f(vh.x) + bf16_f(vl.x);
                    f.y = bf16_f(vh.y) + bf16_f(vl.y);
                    f.z = bf16_f(vh.z) + bf16_f(vl.z);
                    f.w = bf16_f(vh.w) + bf16_f(vl.w);
                    *(float4*)(hrow + rr * 512 + kq) = f;
                }
                __syncthreads();
                // wave w: r=w&3 (batch row), kp=w>>2 (k half); lane = vocab v.
                // projW is transposed [v][k] -> per-lane float4 runs.
                float acc = 0.0f;
                const float* wp = projW + (size_t)v * 512 + kp * 256;
                const float* hp = hrow + r * 512 + kp * 256;
                #pragma unroll 8
                for (int q = 0; q < 64; ++q) {
                    float4 w  = *(const float4*)(wp + q * 4);
                    float4 hq = *(const float4*)(hp + q * 4);
                    acc = fmaf(w.x, hq.x, acc); acc = fmaf(w.y, hq.y, acc);
                    acc = fmaf(w.z, hq.z, acc); acc = fmaf(w.w, hq.w, acc);
                }
                if (kp == 1) parts[r * 64 + v] = acc;
                __syncthreads();
                if (kp == 0) {
                    float logit = acc + parts[r * 64 + v] + pbv;
                    int grow = b0p + r;
                    out[(size_t)B * T + ((size_t)grow * T + tp) * V + v] = logit;
                    float best = logit; int bi = v;
                    #pragma unroll
                    for (int off = 32; off; off >>= 1) {
                        float ov = __shfl_xor(best, off, 64);
                        int oi  = __shfl_xor(bi, off, 64);
                        if (ov > best || (ov == best && oi < bi)) { best = ov; bi = oi; }
                    }
                    if (v == 0) out[(size_t)grow * T + tp] = (float)bi;
                }
            }
            __threadfence();
            grid.sync();
        }
    }
}

// ---------------- prep kernels ----------------
// x interleaved: xI[pos*128 + c*32 + kk] = hi(emb[k=c*16+kk]), +16 = lo
__global__ void embed_split_k(const int* __restrict__ tok, const float* __restrict__ emb,
                              unsigned short* __restrict__ xI)
{
    int idx = blockIdx.x * 256 + threadIdx.x;   // B*T*16 quads
    int pos = idx >> 4, q = idx & 15;
    int c = q >> 2, kk4 = (q & 3) * 4;          // k = q*4 = c*16 + kk4
    int tk = tok[pos];
    float4 v = *(const float4*)(emb + (size_t)tk * V + q * 4);
    ushort4 hh, ll;
    hh.x = bf16_hi(v.x); ll.x = bf16_hi(v.x - bf16_f(hh.x));
    hh.y = bf16_hi(v.y); ll.y = bf16_hi(v.y - bf16_f(hh.y));
    hh.z = bf16_hi(v.z); ll.z = bf16_hi(v.z - bf16_f(hh.z));
    hh.w = bf16_hi(v.w); ll.w = bf16_hi(v.w - bf16_f(hh.w));
    size_t base = (size_t)pos * 128 + c * 32 + kk4;
    *(ushort4*)(xI + base) = hh;
    *(ushort4*)(xI + base + 16) = ll;
}

// weight lo-plane prepack, fragment order (per block ug: [K/8][32][8])
__global__ void wlo_k(const float* __restrict__ Wx, const float* __restrict__ Wh,
                      unsigned short* __restrict__ dst, int K, int Dx)
{
    int idx = blockIdx.x * 256 + threadIdx.x;   // 64 * K * 32
    int ug = idx / (K * 32);
    int rem = idx - ug * (K * 32);
    int k = rem >> 5, n = rem & 31, u = n >> 2, g = n & 3;
    int col = g * 512 + ug * 8 + u;
    float w = (k < Dx) ? Wx[(size_t)k * G4U + col] : Wh[(size_t)(k - Dx) * G4U + col];
    unsigned short hi = bf16_hi(w);
    dst[(size_t)ug * (K * 32) + ((k >> 3) * 32 + n) * 8 + (k & 7)] = bf16_hi(w - bf16_f(hi));
}

__global__ void latent_k(const unsigned short* __restrict__ h2,
                         const float* __restrict__ eps,
                         const float* __restrict__ wm, const float* __restrict__ bm,
                         const float* __restrict__ wsig, const float* __restrict__ bs,
                         float* __restrict__ lat)
{
    __shared__ float hr[U];
    int b = blockIdx.x, l = threadIdx.x;
    {
        size_t o1 = (size_t)b * 1024 + (l >> 4) * 32 + (l & 15);
        int l2 = l + 256;
        size_t o2 = (size_t)b * 1024 + (l2 >> 4) * 32 + (l2 & 15);
        hr[l]  = bf16_f(h2[o1]) + bf16_f(h2[o1 + 16]);
        hr[l2] = bf16_f(h2[o2]) + bf16_f(h2[o2 + 16]);
    }
    __syncthreads();
    float am = bm[l], as = bs[l];
    for (int k = 0; k < U; ++k) {
        float h = hr[k];
        am = fmaf(h, wm[(size_t)k * L + l], am);
        as = fmaf(h, wsig[(size_t)k * L + l], as);
    }
    lat[(size_t)b * L + l] = am + expf(as * 0.5f) * eps[(size_t)b * L + l];
}

// xcr[b][ugi*32+u*4+g] = dec_b0 + latent @ dec_Wx0[0:L]  (col oc = g*512+ugi*8+u)
__global__ void xcr_k(const float* __restrict__ lat, const float* __restrict__ Wx0,
                      const float* __restrict__ b0v, float* __restrict__ xcr)
{
    __shared__ float lr[L];
    int b = blockIdx.x >> 3;
    int oc = (blockIdx.x & 7) * 256 + threadIdx.x;
    lr[threadIdx.x] = lat[(size_t)b * L + threadIdx.x];
    __syncthreads();
    float acc = b0v[oc];
    for (int k = 0; k < L; ++k) acc = fmaf(lr[k], Wx0[(size_t)k * G4U + oc], acc);
    int g = oc >> 9, rest = oc & 511, ugi = rest >> 3, u = rest & 7;
    xcr[(size_t)b * G4U + ugi * 32 + u * 4 + g] = acc;
}

__global__ void biasref_k(const float* s0, const float* s1, const float* s2,
                          const float* s3, const float* s4, float* __restrict__ ebr)
{
    int idx = blockIdx.x * 256 + threadIdx.x;   // 5*2048
    int which = idx >> 11, oc = idx & 2047;
    const float* s = which == 0 ? s0 : which == 1 ? s1 : which == 2 ? s2
                   : which == 3 ? s3 : s4;
    int g = oc >> 9, rest = oc & 511, ugi = rest >> 3, u = rest & 7;
    ebr[which * 2048 + ugi * 32 + u * 4 + g] = s[oc];
}

// Wt[v][k] = dec_W[k][v]  (transposed projection weight, float4-loadable rows)
__global__ void wtprep_k(const float* __restrict__ W, float* __restrict__ Wt)
{
    int idx = blockIdx.x * 256 + threadIdx.x;   // 32768
    int k = idx >> 6, v = idx & 63;
    Wt[(size_t)v * 512 + k] = W[idx];
}

__global__ void sentinel_k(float* __restrict__ out, float val) { out[threadIdx.x] = val; }

extern "C" void kernel_launch(void* const* d_in, const int* in_sizes, int n_in,
                              void* d_out, int out_size, void* d_ws, size_t ws_size,
                              hipStream_t stream)
{
    const int*   tokens   = (const int*)  d_in[0];
    const float* eps      = (const float*)d_in[1];
    const float* emb      = (const float*)d_in[2];
    const float* enc_Wx0  = (const float*)d_in[3];
    const float* enc_Wh0  = (const float*)d_in[4];
    const float* enc_b0   = (const float*)d_in[5];
    const float* enc_Wx12 = (const float*)d_in[6];
    const float* enc_Wh12 = (const float*)d_in[7];
    const float* enc_b12  = (const float*)d_in[8];
    const float* w_mean   = (const float*)d_in[9];
    const float* b_mean   = (const float*)d_in[10];
    const float* w_sigma  = (const float*)d_in[11];
    const float* b_sigma  = (const float*)d_in[12];
    const float* dec_Wx0  = (const float*)d_in[13];
    const float* dec_Wh0  = (const float*)d_in[14];
    const float* dec_b0   = (const float*)d_in[15];
    const float* dec_Wx12 = (const float*)d_in[16];
    const float* dec_Wh12 = (const float*)d_in[17];
    const float* dec_b12  = (const float*)d_in[18];
    const float* dec_W    = (const float*)d_in[19];
    const float* dec_b    = (const float*)d_in[20];
    float* out = (float*)d_out;

    // workspace carve-up (all 16B aligned)
    unsigned short* xI  = (unsigned short*)d_ws;                  // B*T*128 us
    unsigned short* h   = xI + (size_t)B * T * 128;               // 6*HBUF us
    unsigned short* wlo = h + 6 * (size_t)HBUF;                   // WLO_TOTAL us
    float* lat = (float*)(wlo + WLO_TOTAL);                       // B*L
    float* xcr = lat + (size_t)B * L;                             // B*2048
    float* ebr = xcr + (size_t)B * G4U;                           // 5*2048
    float* Wt  = ebr + 5 * G4U;                                   // 64*512
    size_t need = (size_t)((char*)(Wt + 64 * 512) - (char*)d_ws);
    if (ws_size < need) {
        sentinel_k<<<dim3(1), dim3(64), 0, stream>>>(out, -1.0e6f);
        return;
    }

    const size_t UG = (size_t)U * G4U;

    embed_split_k<<<dim3(B * T * 16 / 256), dim3(256), 0, stream>>>(tokens, emb, xI);
    biasref_k<<<dim3(40), dim3(256), 0, stream>>>(enc_b0, enc_b12, enc_b12 + G4U,
                                                  dec_b12, dec_b12 + G4U, ebr);
    wtprep_k<<<dim3(128), dim3(256), 0, stream>>>(dec_W, Wt);

    auto coop = [&](const float* Wx0_, const float* Wh0_,
                    const float* Wx1_, const float* Wh1_,
                    const float* Wx2_, const float* Wh2_,
                    const float* cbb, const float* rb,
                    const float* pW, const float* pB, int np) -> hipError_t {
        const unsigned short* a_xI = xI;
        const unsigned short* a_wlo = wlo;
        unsigned short* a_h = h;
        float* a_out = out;
        void* args[] = { (void*)&a_xI,
                         (void*)&Wx0_, (void*)&Wh0_, (void*)&Wx1_, (void*)&Wh1_,
                         (void*)&Wx2_, (void*)&Wh2_, (void*)&a_wlo,
                         (void*)&cbb, (void*)&rb, (void*)&a_h,
                         (void*)&pW, (void*)&pB, (void*)&a_out, (void*)&np };
        return hipLaunchCooperativeKernel((void*)vae_stack, dim3(256), dim3(512),
                                          args, 0, stream);
    };

    // ---------------- encoder ----------------
    wlo_k<<<dim3(4608), dim3(256), 0, stream>>>(enc_Wx0, enc_Wh0, wlo, 576, 64);
    wlo_k<<<dim3(8192), dim3(256), 0, stream>>>(enc_Wx12, enc_Wh12, wlo + WLO_R1, 1024, 512);
    wlo_k<<<dim3(8192), dim3(256), 0, stream>>>(enc_Wx12 + UG, enc_Wh12 + UG,
                                                wlo + WLO_R2, 1024, 512);
    hipError_t e1 = coop(enc_Wx0, enc_Wh0, enc_Wx12, enc_Wh12,
                         enc_Wx12 + UG, enc_Wh12 + UG,
                         ebr, nullptr, nullptr, nullptr, T + 2);

    // latent head reads encoder h2[t=255] (buf 1): interleaved panel 5
    latent_k<<<dim3(B), dim3(256), 0, stream>>>(h + 5 * (size_t)HBUF,
                                                eps, w_mean, b_mean, w_sigma, b_sigma, lat);
    xcr_k<<<dim3(2048), dim3(256), 0, stream>>>(lat, dec_Wx0, dec_b0, xcr);

    // ---------------- decoder ----------------
    wlo_k<<<dim3(4608), dim3(256), 0, stream>>>(dec_Wx0 + (size_t)L * G4U, dec_Wh0,
                                                wlo, 576, 64);
    wlo_k<<<dim3(8192), dim3(256), 0, stream>>>(dec_Wx12, dec_Wh12, wlo + WLO_R1, 1024, 512);
    wlo_k<<<dim3(8192), dim3(256), 0, stream>>>(dec_Wx12 + UG, dec_Wh12 + UG,
                                                wlo + WLO_R2, 1024, 512);
    hipError_t e2 = coop(dec_Wx0 + (size_t)L * G4U, dec_Wh0, dec_Wx12, dec_Wh12,
                         dec_Wx12 + UG, dec_Wh12 + UG,
                         ebr + 2 * G4U, xcr, Wt, dec_b, T + 3);

    if (e1 != hipSuccess || e2 != hipSuccess) {
        sentinel_k<<<dim3(1), dim3(64), 0, stream>>>(out, -3.0e6f);
    }
}

// Round 7
// 30798.041 us; speedup vs baseline: 6.5975x; 2.0393x over previous
//
#include <hip/hip_runtime.h>
#include <math.h>

#define B 256
#define T 256
#define U 512
#define L 256
#define V 64
#define G4U 2048
#define BU (B * U)
#define HBUF 262144   // ushorts per (layer,buf) interleaved h panel: 256 rows * 1024

// wlo region offsets (ushort elements)
#define WLO_R1 1179648          // 64 * 576 * 32
#define WLO_R2 3276800          // WLO_R1 + 64*1024*32
#define WLO_TOTAL 5373952       // WLO_R2 + 64*1024*32

typedef __attribute__((ext_vector_type(8))) short bf16x8;
typedef __attribute__((ext_vector_type(16))) float f32x16;

__device__ __forceinline__ unsigned short bf16_hi(float x) {
    union { float f; unsigned int u; } c; c.f = x;
    unsigned int r = c.u + 0x7fffu + ((c.u >> 16) & 1u);   // RNE
    return (unsigned short)(r >> 16);
}
__device__ __forceinline__ float bf16_f(unsigned short h) {
    union { unsigned int u; float f; } c; c.u = ((unsigned int)h) << 16;
    return c.f;
}

// Grid barrier: sense-reversing via (cnt, gen) in global memory, AGENT scope.
// All blocks call it the same number of times with increasing ph (0,1,2,...).
// Release-sequence on cnt + release-store of gen + acquire-load on exit gives
// cross-XCD visibility of all pre-barrier writes. ~o(µs) target vs cg's ~115µs.
__device__ __forceinline__ void gridbar(int* cnt, int* gen, int nb, int ph)
{
    __syncthreads();   // all block threads' work (incl. global stores) issued
    if (threadIdx.x == 0) {
        int old = __hip_atomic_fetch_add(cnt, 1, __ATOMIC_ACQ_REL,
                                         __HIP_MEMORY_SCOPE_AGENT);
        if (old == nb - 1) {
            __hip_atomic_store(cnt, 0, __ATOMIC_RELAXED, __HIP_MEMORY_SCOPE_AGENT);
            __hip_atomic_store(gen, ph + 1, __ATOMIC_RELEASE, __HIP_MEMORY_SCOPE_AGENT);
        } else {
            while (__hip_atomic_load(gen, __ATOMIC_RELAXED,
                                     __HIP_MEMORY_SCOPE_AGENT) < ph + 1)
                __builtin_amdgcn_s_sleep(2);
            (void)__hip_atomic_load(gen, __ATOMIC_ACQUIRE, __HIP_MEMORY_SCOPE_AGENT);
        }
    }
    __syncthreads();
}

// Software-pipelined GEMM sub-loop over NCH 16-k chunks (NCH % 4 == 0).
template<int NCH>
__device__ __forceinline__ void gemm_sub(const unsigned short* __restrict__ abase,
                                         const unsigned short* __restrict__ bhiB,
                                         const unsigned short* __restrict__ bloB,
                                         int kh8, f32x16& acc)
{
    constexpr int NB = NCH / 4;
    bf16x8 ah[2][4], al[2][4], bl[2][4];
    #pragma unroll
    for (int i = 0; i < 4; ++i) {
        ah[0][i] = *(const bf16x8*)(abase + i * 32 + kh8);
        al[0][i] = *(const bf16x8*)(abase + i * 32 + 16 + kh8);
        bl[0][i] = *(const bf16x8*)(bloB + i * 512);
    }
    #pragma unroll
    for (int b = 0; b < NB; ++b) {
        const int cur = b & 1, nxt = cur ^ 1;
        if (b + 1 < NB) {
            #pragma unroll
            for (int i = 0; i < 4; ++i) {
                const int c = (b + 1) * 4 + i;
                ah[nxt][i] = *(const bf16x8*)(abase + c * 32 + kh8);
                al[nxt][i] = *(const bf16x8*)(abase + c * 32 + 16 + kh8);
                bl[nxt][i] = *(const bf16x8*)(bloB + c * 512);
            }
        }
        #pragma unroll
        for (int i = 0; i < 4; ++i) {
            const int c = b * 4 + i;
            bf16x8 bh = *(const bf16x8*)(bhiB + c * 512);
            acc = __builtin_amdgcn_mfma_f32_32x32x16_bf16(ah[cur][i], bh, acc, 0, 0, 0);
            acc = __builtin_amdgcn_mfma_f32_32x32x16_bf16(ah[cur][i], bl[cur][i], acc, 0, 0, 0);
            acc = __builtin_amdgcn_mfma_f32_32x32x16_bf16(al[cur][i], bh, acc, 0, 0, 0);
        }
    }
}

// Fused 3-layer LSTM stack, diagonal-pipelined, split-bf16 MFMA.
// Blocks 0-63: layer0; 64-127: layer1; 128-191: layer2; 192-255: projection.
// LDS: 64KB static (weight hi-plane). Weight lo-plane prepacked in global.
// Custom gridbar replaces cg::grid.sync (the measured ~115µs/phase cost).
__global__ void __launch_bounds__(512, 1)
vae_stack(const unsigned short* __restrict__ xI,
          const float* __restrict__ Wx0, const float* __restrict__ Wh0,
          const float* __restrict__ Wx1, const float* __restrict__ Wh1,
          const float* __restrict__ Wx2, const float* __restrict__ Wh2,
          const unsigned short* __restrict__ wlo,
          const float* __restrict__ cb_base, const float* __restrict__ rb0,
          unsigned short* __restrict__ h,
          const float* __restrict__ projW, const float* __restrict__ projB,
          float* __restrict__ out, int nphase, int* __restrict__ bar)
{
    __shared__ __align__(16) char smem[65536];
    int* bcnt = bar;
    int* bgen = bar + 16;   // 64B apart from cnt
    const int nb = gridDim.x;
    const int tid = threadIdx.x;
    const int bid = blockIdx.x;
    const int role = bid >> 6;
    const int ug = bid & 63;
    const int lane = tid & 63;
    const int wv = tid >> 6;        // wave id
    const int m0 = wv * 32;

    // zero all h buffers (6 interleaved panels), 1 slice per thread, nt stores
    {
        unsigned int* hz = (unsigned int*)h;
        int gid = bid * 512 + tid;
        #pragma unroll
        for (int i = 0; i < 6; ++i)
            __builtin_nontemporal_store(0u, hz + gid + i * 131072);
    }

    auto HP = [&](int layer, int buf) -> unsigned short* {
        return h + (size_t)(layer * 2 + buf) * HBUF;
    };

    if (role < 3) {
        const int K  = (role == 0) ? 576 : 1024;
        const int Dx = (role == 0) ? 64 : 512;
        unsigned short* Whi = (unsigned short*)smem;    // [K/8][32][8], <=64KB

        // one-time weight hi-plane stage (col slot n = u*4+g; col = g*512+ug*8+u)
        const float* WxL = (role == 0) ? Wx0 : ((role == 1) ? Wx1 : Wx2);
        const float* WhL = (role == 0) ? Wh0 : ((role == 1) ? Wh1 : Wh2);
        for (int idx = tid; idx < K * 32; idx += 512) {
            int k = idx >> 5, n = idx & 31, u = n >> 2, g = n & 3;
            int col = g * 512 + ug * 8 + u;
            float w = (k < Dx) ? WxL[(size_t)k * G4U + col]
                               : WhL[(size_t)(k - Dx) * G4U + col];
            Whi[((k >> 3) * 32 + n) * 8 + (k & 7)] = bf16_hi(w);
        }
        const unsigned short* wloB =
            (role == 0) ? wlo + (size_t)ug * (576 * 32)
                        : wlo + WLO_R1 + (size_t)(role - 1) * 2097152 + (size_t)ug * 32768;

        const bool userb = (role == 0) && (rb0 != nullptr);
        const float colbias = userb ? 0.0f
                            : cb_base[role * 2048 + ug * 32 + (lane & 31)];
        float cst[16];
        #pragma unroll
        for (int i = 0; i < 16; ++i) cst[i] = 0.0f;

        const int arow = m0 + (lane & 31);      // A row (batch)
        const int kh8  = (lane >> 5) * 8;       // k-half offset in 16-chunk
        const int frg  = (lane >> 5) * 256 + (lane & 31) * 8;  // B frag offset

        gridbar(bcnt, bgen, nb, 0);

        for (int p = 0; p < nphase; ++p) {
            const int t = p - role;
            if (t >= 0 && t < T) {
                const int wr = t & 1, rd = wr ^ 1;
                f32x16 acc;
                #pragma unroll
                for (int i = 0; i < 16; ++i) acc[i] = 0.0f;

                if (role == 0) {
                    gemm_sub<4>(xI + ((size_t)arow * T + t) * 128,
                                Whi + frg, wloB + frg, kh8, acc);
                    gemm_sub<32>(HP(0, rd) + (size_t)arow * 1024,
                                 Whi + 4 * 512 + frg, wloB + 4 * 512 + frg, kh8, acc);
                } else {
                    gemm_sub<32>(HP(role - 1, wr) + (size_t)arow * 1024,
                                 Whi + frg, wloB + frg, kh8, acc);
                    gemm_sub<32>(HP(role, rd) + (size_t)arow * 1024,
                                 Whi + 32 * 512 + frg, wloB + 32 * 512 + frg, kh8, acc);
                }

                // pointwise: C layout col=lane&31, row=(r&3)+8*(r>>2)+4*(lane>>5)
                const int n = lane & 31, g = n & 3, u8 = n >> 2, hi5 = lane >> 5;
                unsigned short* hw = HP(role, wr);
                const int gu = ug * 8 + u8;
                const int guo = (gu >> 4) * 32 + (gu & 15);   // interleaved offset
                const bool g1 = (g & 1), g2 = (g & 2);
                #pragma unroll
                for (int r = 0; r < 16; ++r) {
                    int grow = m0 + (r & 3) + 8 * (r >> 2) + 4 * hi5;
                    float z = acc[r] + colbias;
                    if (userb) z += rb0[(size_t)grow * G4U + ug * 32 + n];
                    float zb = __shfl_xor(z, 1, 64);
                    float zc = __shfl_xor(z, 2, 64);
                    float zd = __shfl_xor(z, 3, 64);
                    float t01 = g1 ? zb : z,  t23 = g1 ? zd : zc;
                    float u01 = g1 ? z  : zb, u23 = g1 ? zc : zd;
                    float zi = g2 ? t23 : t01;
                    float zf = g2 ? u23 : u01;
                    float zG = g2 ? t01 : t23;
                    float zo = g2 ? u01 : u23;
                    float ig = 1.0f / (1.0f + expf(-zi));
                    float fg = 1.0f / (1.0f + expf(-zf));
                    float gg = tanhf(zG);
                    float og = 1.0f / (1.0f + expf(-zo));
                    cst[r] = fg * cst[r] + ig * gg;
                    float hv = og * tanhf(cst[r]);
                    if (g == 0) {
                        unsigned short hh2 = bf16_hi(hv);
                        unsigned short hl2 = bf16_hi(hv - bf16_f(hh2));
                        size_t ho = (size_t)grow * 1024 + guo;
                        __builtin_nontemporal_store(hh2, hw + ho);
                        __builtin_nontemporal_store(hl2, hw + ho + 16);
                    }
                }
            }
            gridbar(bcnt, bgen, nb, p + 1);
        }
    } else {
        // ---------------- projection + argmax (decoder) / idle (encoder) ----
        float* hrow  = (float*)smem;            // [4][512]
        float* parts = (float*)(smem + 8192);   // [256]
        const int b0p = ug * 4;
        const float pbv = projW ? projB[lane] : 0.0f;
        const int r = wv & 3, kp = wv >> 2, v = lane;
        gridbar(bcnt, bgen, nb, 0);
        for (int p = 0; p < nphase; ++p) {
            const int tp = p - 3;
            if (projW && tp >= 0 && tp < T) {
                {   // stage 4 h2 rows (hi+lo recon) into LDS
                    int rr = tid >> 7, kq = (tid & 127) * 4;   // 4 units, same chunk
                    const unsigned short* hb2 = HP(2, tp & 1)
                        + (size_t)(b0p + rr) * 1024 + (kq >> 4) * 32 + (kq & 15);
                    ushort4 vh = *(const ushort4*)hb2;
                    ushort4 vl = *(const ushort4*)(hb2 + 16);
                    float4 f;
                    f.x = bf16_f(vh.x) + bf16_f(vl.x);
                    f.y = bf16_f(vh.y) + bf16_f(vl.y);
                    f.z = bf16_f(vh.z) + bf16_f(vl.z);
                    f.w = bf16_f(vh.w) + bf16_f(vl.w);
                    *(float4*)(hrow + rr * 512 + kq) = f;
                }
                __syncthreads();
                // wave w: r=w&3 (batch row), kp=w>>2 (k half); lane = vocab v.
                float acc = 0.0f;
                const float* wp = projW + (size_t)v * 512 + kp * 256;
                const float* hp = hrow + r * 512 + kp * 256;
                #pragma unroll 8
                for (int q = 0; q < 64; ++q) {
                    float4 w  = *(const float4*)(wp + q * 4);
                    float4 hq = *(const float4*)(hp + q * 4);
                    acc = fmaf(w.x, hq.x, acc); acc = fmaf(w.y, hq.y, acc);
                    acc = fmaf(w.z, hq.z, acc); acc = fmaf(w.w, hq.w, acc);
                }
                if (kp == 1) parts[r * 64 + v] = acc;
                __syncthreads();
                if (kp == 0) {
                    float logit = acc + parts[r * 64 + v] + pbv;
                    int grow = b0p + r;
                    __builtin_nontemporal_store(
                        logit, &out[(size_t)B * T + ((size_t)grow * T + tp) * V + v]);
                    float best = logit; int bi = v;
                    #pragma unroll
                    for (int off = 32; off; off >>= 1) {
                        float ov = __shfl_xor(best, off, 64);
                        int oi  = __shfl_xor(bi, off, 64);
                        if (ov > best || (ov == best && oi < bi)) { best = ov; bi = oi; }
                    }
                    if (v == 0)
                        __builtin_nontemporal_store((float)bi,
                                                    &out[(size_t)grow * T + tp]);
                }
            }
            gridbar(bcnt, bgen, nb, p + 1);
        }
    }
}

// ---------------- prep kernels ----------------
// x interleaved: xI[pos*128 + c*32 + kk] = hi(emb[k=c*16+kk]), +16 = lo
__global__ void embed_split_k(const int* __restrict__ tok, const float* __restrict__ emb,
                              unsigned short* __restrict__ xI)
{
    int idx = blockIdx.x * 256 + threadIdx.x;   // B*T*16 quads
    int pos = idx >> 4, q = idx & 15;
    int c = q >> 2, kk4 = (q & 3) * 4;          // k = q*4 = c*16 + kk4
    int tk = tok[pos];
    float4 v = *(const float4*)(emb + (size_t)tk * V + q * 4);
    ushort4 hh, ll;
    hh.x = bf16_hi(v.x); ll.x = bf16_hi(v.x - bf16_f(hh.x));
    hh.y = bf16_hi(v.y); ll.y = bf16_hi(v.y - bf16_f(hh.y));
    hh.z = bf16_hi(v.z); ll.z = bf16_hi(v.z - bf16_f(hh.z));
    hh.w = bf16_hi(v.w); ll.w = bf16_hi(v.w - bf16_f(hh.w));
    size_t base = (size_t)pos * 128 + c * 32 + kk4;
    *(ushort4*)(xI + base) = hh;
    *(ushort4*)(xI + base + 16) = ll;
}

// weight lo-plane prepack, fragment order (per block ug: [K/8][32][8])
__global__ void wlo_k(const float* __restrict__ Wx, const float* __restrict__ Wh,
                      unsigned short* __restrict__ dst, int K, int Dx)
{
    int idx = blockIdx.x * 256 + threadIdx.x;   // 64 * K * 32
    int ug = idx / (K * 32);
    int rem = idx - ug * (K * 32);
    int k = rem >> 5, n = rem & 31, u = n >> 2, g = n & 3;
    int col = g * 512 + ug * 8 + u;
    float w = (k < Dx) ? Wx[(size_t)k * G4U + col] : Wh[(size_t)(k - Dx) * G4U + col];
    unsigned short hi = bf16_hi(w);
    dst[(size_t)ug * (K * 32) + ((k >> 3) * 32 + n) * 8 + (k & 7)] = bf16_hi(w - bf16_f(hi));
}

__global__ void latent_k(const unsigned short* __restrict__ h2,
                         const float* __restrict__ eps,
                         const float* __restrict__ wm, const float* __restrict__ bm,
                         const float* __restrict__ wsig, const float* __restrict__ bs,
                         float* __restrict__ lat)
{
    __shared__ float hr[U];
    int b = blockIdx.x, l = threadIdx.x;
    {
        size_t o1 = (size_t)b * 1024 + (l >> 4) * 32 + (l & 15);
        int l2 = l + 256;
        size_t o2 = (size_t)b * 1024 + (l2 >> 4) * 32 + (l2 & 15);
        hr[l]  = bf16_f(h2[o1]) + bf16_f(h2[o1 + 16]);
        hr[l2] = bf16_f(h2[o2]) + bf16_f(h2[o2 + 16]);
    }
    __syncthreads();
    float am = bm[l], as = bs[l];
    for (int k = 0; k < U; ++k) {
        float h = hr[k];
        am = fmaf(h, wm[(size_t)k * L + l], am);
        as = fmaf(h, wsig[(size_t)k * L + l], as);
    }
    lat[(size_t)b * L + l] = am + expf(as * 0.5f) * eps[(size_t)b * L + l];
}

// xcr[b][ugi*32+u*4+g] = dec_b0 + latent @ dec_Wx0[0:L]  (col oc = g*512+ugi*8+u)
__global__ void xcr_k(const float* __restrict__ lat, const float* __restrict__ Wx0,
                      const float* __restrict__ b0v, float* __restrict__ xcr)
{
    __shared__ float lr[L];
    int b = blockIdx.x >> 3;
    int oc = (blockIdx.x & 7) * 256 + threadIdx.x;
    lr[threadIdx.x] = lat[(size_t)b * L + threadIdx.x];
    __syncthreads();
    float acc = b0v[oc];
    for (int k = 0; k < L; ++k) acc = fmaf(lr[k], Wx0[(size_t)k * G4U + oc], acc);
    int g = oc >> 9, rest = oc & 511, ugi = rest >> 3, u = rest & 7;
    xcr[(size_t)b * G4U + ugi * 32 + u * 4 + g] = acc;
}

__global__ void biasref_k(const float* s0, const float* s1, const float* s2,
                          const float* s3, const float* s4, float* __restrict__ ebr)
{
    int idx = blockIdx.x * 256 + threadIdx.x;   // 5*2048
    int which = idx >> 11, oc = idx & 2047;
    const float* s = which == 0 ? s0 : which == 1 ? s1 : which == 2 ? s2
                   : which == 3 ? s3 : s4;
    int g = oc >> 9, rest = oc & 511, ugi = rest >> 3, u = rest & 7;
    ebr[which * 2048 + ugi * 32 + u * 4 + g] = s[oc];
}

// Wt[v][k] = dec_W[k][v]  (transposed projection weight, float4-loadable rows)
__global__ void wtprep_k(const float* __restrict__ W, float* __restrict__ Wt)
{
    int idx = blockIdx.x * 256 + threadIdx.x;   // 32768
    int k = idx >> 6, v = idx & 63;
    Wt[(size_t)v * 512 + k] = W[idx];
}

__global__ void barinit_k(int* __restrict__ bar) { bar[0] = 0; bar[16] = 0; }

__global__ void sentinel_k(float* __restrict__ out, float val) { out[threadIdx.x] = val; }

extern "C" void kernel_launch(void* const* d_in, const int* in_sizes, int n_in,
                              void* d_out, int out_size, void* d_ws, size_t ws_size,
                              hipStream_t stream)
{
    const int*   tokens   = (const int*)  d_in[0];
    const float* eps      = (const float*)d_in[1];
    const float* emb      = (const float*)d_in[2];
    const float* enc_Wx0  = (const float*)d_in[3];
    const float* enc_Wh0  = (const float*)d_in[4];
    const float* enc_b0   = (const float*)d_in[5];
    const float* enc_Wx12 = (const float*)d_in[6];
    const float* enc_Wh12 = (const float*)d_in[7];
    const float* enc_b12  = (const float*)d_in[8];
    const float* w_mean   = (const float*)d_in[9];
    const float* b_mean   = (const float*)d_in[10];
    const float* w_sigma  = (const float*)d_in[11];
    const float* b_sigma  = (const float*)d_in[12];
    const float* dec_Wx0  = (const float*)d_in[13];
    const float* dec_Wh0  = (const float*)d_in[14];
    const float* dec_b0   = (const float*)d_in[15];
    const float* dec_Wx12 = (const float*)d_in[16];
    const float* dec_Wh12 = (const float*)d_in[17];
    const float* dec_b12  = (const float*)d_in[18];
    const float* dec_W    = (const float*)d_in[19];
    const float* dec_b    = (const float*)d_in[20];
    float* out = (float*)d_out;

    // workspace carve-up (all 16B aligned)
    unsigned short* xI  = (unsigned short*)d_ws;                  // B*T*128 us
    unsigned short* h   = xI + (size_t)B * T * 128;               // 6*HBUF us
    unsigned short* wlo = h + 6 * (size_t)HBUF;                   // WLO_TOTAL us
    float* lat = (float*)(wlo + WLO_TOTAL);                       // B*L
    float* xcr = lat + (size_t)B * L;                             // B*2048
    float* ebr = xcr + (size_t)B * G4U;                           // 5*2048
    float* Wt  = ebr + 5 * G4U;                                   // 64*512
    int*   bar = (int*)(Wt + 64 * 512);                           // 32 ints
    size_t need = (size_t)((char*)(bar + 32) - (char*)d_ws);
    if (ws_size < need) {
        sentinel_k<<<dim3(1), dim3(64), 0, stream>>>(out, -1.0e6f);
        return;
    }

    const size_t UG = (size_t)U * G4U;

    embed_split_k<<<dim3(B * T * 16 / 256), dim3(256), 0, stream>>>(tokens, emb, xI);
    biasref_k<<<dim3(40), dim3(256), 0, stream>>>(enc_b0, enc_b12, enc_b12 + G4U,
                                                  dec_b12, dec_b12 + G4U, ebr);
    wtprep_k<<<dim3(128), dim3(256), 0, stream>>>(dec_W, Wt);

    auto coop = [&](const float* Wx0_, const float* Wh0_,
                    const float* Wx1_, const float* Wh1_,
                    const float* Wx2_, const float* Wh2_,
                    const float* cbb, const float* rb,
                    const float* pW, const float* pB, int np) -> hipError_t {
        const unsigned short* a_xI = xI;
        const unsigned short* a_wlo = wlo;
        unsigned short* a_h = h;
        float* a_out = out;
        int* a_bar = bar;
        void* args[] = { (void*)&a_xI,
                         (void*)&Wx0_, (void*)&Wh0_, (void*)&Wx1_, (void*)&Wh1_,
                         (void*)&Wx2_, (void*)&Wh2_, (void*)&a_wlo,
                         (void*)&cbb, (void*)&rb, (void*)&a_h,
                         (void*)&pW, (void*)&pB, (void*)&a_out, (void*)&np,
                         (void*)&a_bar };
        return hipLaunchCooperativeKernel((void*)vae_stack, dim3(256), dim3(512),
                                          args, 0, stream);
    };

    // ---------------- encoder ----------------
    wlo_k<<<dim3(4608), dim3(256), 0, stream>>>(enc_Wx0, enc_Wh0, wlo, 576, 64);
    wlo_k<<<dim3(8192), dim3(256), 0, stream>>>(enc_Wx12, enc_Wh12, wlo + WLO_R1, 1024, 512);
    wlo_k<<<dim3(8192), dim3(256), 0, stream>>>(enc_Wx12 + UG, enc_Wh12 + UG,
                                                wlo + WLO_R2, 1024, 512);
    barinit_k<<<dim3(1), dim3(1), 0, stream>>>(bar);
    hipError_t e1 = coop(enc_Wx0, enc_Wh0, enc_Wx12, enc_Wh12,
                         enc_Wx12 + UG, enc_Wh12 + UG,
                         ebr, nullptr, nullptr, nullptr, T + 2);

    // latent head reads encoder h2[t=255] (buf 1): interleaved panel 5
    latent_k<<<dim3(B), dim3(256), 0, stream>>>(h + 5 * (size_t)HBUF,
                                                eps, w_mean, b_mean, w_sigma, b_sigma, lat);
    xcr_k<<<dim3(2048), dim3(256), 0, stream>>>(lat, dec_Wx0, dec_b0, xcr);

    // ---------------- decoder ----------------
    wlo_k<<<dim3(4608), dim3(256), 0, stream>>>(dec_Wx0 + (size_t)L * G4U, dec_Wh0,
                                                wlo, 576, 64);
    wlo_k<<<dim3(8192), dim3(256), 0, stream>>>(dec_Wx12, dec_Wh12, wlo + WLO_R1, 1024, 512);
    wlo_k<<<dim3(8192), dim3(256), 0, stream>>>(dec_Wx12 + UG, dec_Wh12 + UG,
                                                wlo + WLO_R2, 1024, 512);
    barinit_k<<<dim3(1), dim3(1), 0, stream>>>(bar);
    hipError_t e2 = coop(dec_Wx0 + (size_t)L * G4U, dec_Wh0, dec_Wx12, dec_Wh12,
                         dec_Wx12 + UG, dec_Wh12 + UG,
                         ebr + 2 * G4U, xcr, Wt, dec_b, T + 3);

    if (e1 != hipSuccess || e2 != hipSuccess) {
        sentinel_k<<<dim3(1), dim3(64), 0, stream>>>(out, -3.0e6f);
    }
}

// Round 8
// 27095.331 us; speedup vs baseline: 7.4990x; 1.1367x over previous
//
#include <hip/hip_runtime.h>
#include <math.h>

#define B 256
#define T 256
#define U 512
#define L 256
#define V 64
#define G4U 2048
#define BU (B * U)
#define HBUF 262144   // ushorts per (layer,buf) interleaved h panel: 256 rows * 1024

// wlo region offsets (ushort elements)
#define WLO_R1 1179648          // 64 * 576 * 32
#define WLO_R2 3276800          // WLO_R1 + 64*1024*32
#define WLO_TOTAL 5373952       // WLO_R2 + 64*1024*32

typedef __attribute__((ext_vector_type(8))) short bf16x8;
typedef __attribute__((ext_vector_type(16))) float f32x16;

__device__ __forceinline__ unsigned short bf16_hi(float x) {
    union { float f; unsigned int u; } c; c.f = x;
    unsigned int r = c.u + 0x7fffu + ((c.u >> 16) & 1u);   // RNE
    return (unsigned short)(r >> 16);
}
__device__ __forceinline__ float bf16_f(unsigned short h) {
    union { unsigned int u; float f; } c; c.u = ((unsigned int)h) << 16;
    return c.f;
}

// Two-level tree grid barrier, monotonic counters (no reset), AGENT scope.
// Leaves: bar[leaf*16], leaf = bid&7 (8 leaves, 64B apart; ~same-XCD under
// round-robin dispatch). Root: bar[128]. Gen: bar[144].
// Arrival fan-in: 32 parallel RMWs/leaf + 8 root RMWs vs 256 serialized (R7).
// HB: member -(rel/acq leaf)-> leaf-last -(rel/acq root)-> root-last
//     -(rel gen)-> acquire-load gen by all.
__device__ __forceinline__ void gridbar(int* bar, int nbpl, int ph, int leaf)
{
    __syncthreads();   // all block threads' work (incl. global stores) issued
    if (threadIdx.x == 0) {
        int* lc  = bar + leaf * 16;
        int* rc  = bar + 128;
        int* gen = bar + 144;
        int old = __hip_atomic_fetch_add(lc, 1, __ATOMIC_ACQ_REL,
                                         __HIP_MEMORY_SCOPE_AGENT);
        if (old == nbpl * (ph + 1) - 1) {          // last of this leaf, this phase
            int ro = __hip_atomic_fetch_add(rc, 1, __ATOMIC_ACQ_REL,
                                            __HIP_MEMORY_SCOPE_AGENT);
            if (ro == 8 * (ph + 1) - 1) {          // last leaf overall
                __hip_atomic_store(gen, ph + 1, __ATOMIC_RELEASE,
                                   __HIP_MEMORY_SCOPE_AGENT);
            }
        }
        while (__hip_atomic_load(gen, __ATOMIC_RELAXED,
                                 __HIP_MEMORY_SCOPE_AGENT) < ph + 1)
            __builtin_amdgcn_s_sleep(2);
        (void)__hip_atomic_load(gen, __ATOMIC_ACQUIRE, __HIP_MEMORY_SCOPE_AGENT);
    }
    __syncthreads();
}

// Software-pipelined GEMM sub-loop over NCH 16-k chunks (NCH % 4 == 0).
template<int NCH>
__device__ __forceinline__ void gemm_sub(const unsigned short* __restrict__ abase,
                                         const unsigned short* __restrict__ bhiB,
                                         const unsigned short* __restrict__ bloB,
                                         int kh8, f32x16& acc)
{
    constexpr int NB = NCH / 4;
    bf16x8 ah[2][4], al[2][4], bl[2][4];
    #pragma unroll
    for (int i = 0; i < 4; ++i) {
        ah[0][i] = *(const bf16x8*)(abase + i * 32 + kh8);
        al[0][i] = *(const bf16x8*)(abase + i * 32 + 16 + kh8);
        bl[0][i] = *(const bf16x8*)(bloB + i * 512);
    }
    #pragma unroll
    for (int b = 0; b < NB; ++b) {
        const int cur = b & 1, nxt = cur ^ 1;
        if (b + 1 < NB) {
            #pragma unroll
            for (int i = 0; i < 4; ++i) {
                const int c = (b + 1) * 4 + i;
                ah[nxt][i] = *(const bf16x8*)(abase + c * 32 + kh8);
                al[nxt][i] = *(const bf16x8*)(abase + c * 32 + 16 + kh8);
                bl[nxt][i] = *(const bf16x8*)(bloB + c * 512);
            }
        }
        #pragma unroll
        for (int i = 0; i < 4; ++i) {
            const int c = b * 4 + i;
            bf16x8 bh = *(const bf16x8*)(bhiB + c * 512);
            acc = __builtin_amdgcn_mfma_f32_32x32x16_bf16(ah[cur][i], bh, acc, 0, 0, 0);
            acc = __builtin_amdgcn_mfma_f32_32x32x16_bf16(ah[cur][i], bl[cur][i], acc, 0, 0, 0);
            acc = __builtin_amdgcn_mfma_f32_32x32x16_bf16(al[cur][i], bh, acc, 0, 0, 0);
        }
    }
}

// Fused 3-layer LSTM stack, diagonal-pipelined, split-bf16 MFMA.
// Blocks 0-63: layer0; 64-127: layer1; 128-191: layer2; 192-255: projection
// (decoder only; encoder launches 192 blocks).
__global__ void __launch_bounds__(512, 1)
vae_stack(const unsigned short* __restrict__ xI,
          const float* __restrict__ Wx0, const float* __restrict__ Wh0,
          const float* __restrict__ Wx1, const float* __restrict__ Wh1,
          const float* __restrict__ Wx2, const float* __restrict__ Wh2,
          const unsigned short* __restrict__ wlo,
          const float* __restrict__ cb_base, const float* __restrict__ rb0,
          unsigned short* __restrict__ h,
          const float* __restrict__ projW, const float* __restrict__ projB,
          float* __restrict__ out, int nphase, int* __restrict__ bar)
{
    __shared__ __align__(16) char smem[65536];
    const int nb = gridDim.x;
    const int nbpl = nb >> 3;       // blocks per leaf (256->32, 192->24)
    const int tid = threadIdx.x;
    const int bid = blockIdx.x;
    const int leaf = bid & 7;
    const int role = bid >> 6;
    const int ug = bid & 63;
    const int lane = tid & 63;
    const int wv = tid >> 6;        // wave id
    const int m0 = wv * 32;

    // zero all h buffers (6 interleaved panels = 786432 uints), grid-stride
    {
        unsigned int* hz = (unsigned int*)h;
        const int stride = nb * 512;
        for (int i = bid * 512 + tid; i < 786432; i += stride)
            __builtin_nontemporal_store(0u, hz + i);
    }

    auto HP = [&](int layer, int buf) -> unsigned short* {
        return h + (size_t)(layer * 2 + buf) * HBUF;
    };

    if (role < 3) {
        const int K  = (role == 0) ? 576 : 1024;
        const int Dx = (role == 0) ? 64 : 512;
        unsigned short* Whi = (unsigned short*)smem;    // [K/8][32][8], <=64KB

        // one-time weight hi-plane stage (col slot n = u*4+g; col = g*512+ug*8+u)
        const float* WxL = (role == 0) ? Wx0 : ((role == 1) ? Wx1 : Wx2);
        const float* WhL = (role == 0) ? Wh0 : ((role == 1) ? Wh1 : Wh2);
        for (int idx = tid; idx < K * 32; idx += 512) {
            int k = idx >> 5, n = idx & 31, u = n >> 2, g = n & 3;
            int col = g * 512 + ug * 8 + u;
            float w = (k < Dx) ? WxL[(size_t)k * G4U + col]
                               : WhL[(size_t)(k - Dx) * G4U + col];
            Whi[((k >> 3) * 32 + n) * 8 + (k & 7)] = bf16_hi(w);
        }
        const unsigned short* wloB =
            (role == 0) ? wlo + (size_t)ug * (576 * 32)
                        : wlo + WLO_R1 + (size_t)(role - 1) * 2097152 + (size_t)ug * 32768;

        const bool userb = (role == 0) && (rb0 != nullptr);
        const float colbias = userb ? 0.0f
                            : cb_base[role * 2048 + ug * 32 + (lane & 31)];
        float cst[16];
        #pragma unroll
        for (int i = 0; i < 16; ++i) cst[i] = 0.0f;

        const int arow = m0 + (lane & 31);      // A row (batch)
        const int kh8  = (lane >> 5) * 8;       // k-half offset in 16-chunk
        const int frg  = (lane >> 5) * 256 + (lane & 31) * 8;  // B frag offset

        gridbar(bar, nbpl, 0, leaf);

        for (int p = 0; p < nphase; ++p) {
            const int t = p - role;
            if (t >= 0 && t < T) {
                const int wr = t & 1, rd = wr ^ 1;
                f32x16 acc;
                #pragma unroll
                for (int i = 0; i < 16; ++i) acc[i] = 0.0f;

                if (role == 0) {
                    gemm_sub<4>(xI + ((size_t)arow * T + t) * 128,
                                Whi + frg, wloB + frg, kh8, acc);
                    gemm_sub<32>(HP(0, rd) + (size_t)arow * 1024,
                                 Whi + 4 * 512 + frg, wloB + 4 * 512 + frg, kh8, acc);
                } else {
                    gemm_sub<32>(HP(role - 1, wr) + (size_t)arow * 1024,
                                 Whi + frg, wloB + frg, kh8, acc);
                    gemm_sub<32>(HP(role, rd) + (size_t)arow * 1024,
                                 Whi + 32 * 512 + frg, wloB + 32 * 512 + frg, kh8, acc);
                }

                // pointwise: C layout col=lane&31, row=(r&3)+8*(r>>2)+4*(lane>>5)
                const int n = lane & 31, g = n & 3, u8 = n >> 2, hi5 = lane >> 5;
                unsigned short* hw = HP(role, wr);
                const int gu = ug * 8 + u8;
                const int guo = (gu >> 4) * 32 + (gu & 15);   // interleaved offset
                const bool g1 = (g & 1), g2 = (g & 2);
                #pragma unroll
                for (int r = 0; r < 16; ++r) {
                    int grow = m0 + (r & 3) + 8 * (r >> 2) + 4 * hi5;
                    float z = acc[r] + colbias;
                    if (userb) z += rb0[(size_t)grow * G4U + ug * 32 + n];
                    float zb = __shfl_xor(z, 1, 64);
                    float zc = __shfl_xor(z, 2, 64);
                    float zd = __shfl_xor(z, 3, 64);
                    float t01 = g1 ? zb : z,  t23 = g1 ? zd : zc;
                    float u01 = g1 ? z  : zb, u23 = g1 ? zc : zd;
                    float zi = g2 ? t23 : t01;
                    float zf = g2 ? u23 : u01;
                    float zG = g2 ? t01 : t23;
                    float zo = g2 ? u01 : u23;
                    float ig = 1.0f / (1.0f + expf(-zi));
                    float fg = 1.0f / (1.0f + expf(-zf));
                    float gg = tanhf(zG);
                    float og = 1.0f / (1.0f + expf(-zo));
                    cst[r] = fg * cst[r] + ig * gg;
                    float hv = og * tanhf(cst[r]);
                    if (g == 0) {
                        unsigned short hh2 = bf16_hi(hv);
                        unsigned short hl2 = bf16_hi(hv - bf16_f(hh2));
                        size_t ho = (size_t)grow * 1024 + guo;
                        __builtin_nontemporal_store(hh2, hw + ho);
                        __builtin_nontemporal_store(hl2, hw + ho + 16);
                    }
                }
            }
            gridbar(bar, nbpl, p + 1, leaf);
        }
    } else {
        // ---------------- projection + argmax (decoder only) ----------------
        float* hrow  = (float*)smem;            // [4][512]
        float* parts = (float*)(smem + 8192);   // [256]
        const int b0p = ug * 4;
        const float pbv = projW ? projB[lane] : 0.0f;
        const int r = wv & 3, kp = wv >> 2, v = lane;
        gridbar(bar, nbpl, 0, leaf);
        for (int p = 0; p < nphase; ++p) {
            const int tp = p - 3;
            if (projW && tp >= 0 && tp < T) {
                {   // stage 4 h2 rows (hi+lo recon) into LDS
                    int rr = tid >> 7, kq = (tid & 127) * 4;   // 4 units, same chunk
                    const unsigned short* hb2 = HP(2, tp & 1)
                        + (size_t)(b0p + rr) * 1024 + (kq >> 4) * 32 + (kq & 15);
                    ushort4 vh = *(const ushort4*)hb2;
                    ushort4 vl = *(const ushort4*)(hb2 + 16);
                    float4 f;
                    f.x = bf16_f(vh.x) + bf16_f(vl.x);
                    f.y = bf16_f(vh.y) + bf16_f(vl.y);
                    f.z = bf16_f(vh.z) + bf16_f(vl.z);
                    f.w = bf16_f(vh.w) + bf16_f(vl.w);
                    *(float4*)(hrow + rr * 512 + kq) = f;
                }
                __syncthreads();
                // wave w: r=w&3 (batch row), kp=w>>2 (k half); lane = vocab v.
                float acc = 0.0f;
                const float* wp = projW + (size_t)v * 512 + kp * 256;
                const float* hp = hrow + r * 512 + kp * 256;
                #pragma unroll 8
                for (int q = 0; q < 64; ++q) {
                    float4 w  = *(const float4*)(wp + q * 4);
                    float4 hq = *(const float4*)(hp + q * 4);
                    acc = fmaf(w.x, hq.x, acc); acc = fmaf(w.y, hq.y, acc);
                    acc = fmaf(w.z, hq.z, acc); acc = fmaf(w.w, hq.w, acc);
                }
                if (kp == 1) parts[r * 64 + v] = acc;
                __syncthreads();
                if (kp == 0) {
                    float logit = acc + parts[r * 64 + v] + pbv;
                    int grow = b0p + r;
                    __builtin_nontemporal_store(
                        logit, &out[(size_t)B * T + ((size_t)grow * T + tp) * V + v]);
                    float best = logit; int bi = v;
                    #pragma unroll
                    for (int off = 32; off; off >>= 1) {
                        float ov = __shfl_xor(best, off, 64);
                        int oi  = __shfl_xor(bi, off, 64);
                        if (ov > best || (ov == best && oi < bi)) { best = ov; bi = oi; }
                    }
                    if (v == 0)
                        __builtin_nontemporal_store((float)bi,
                                                    &out[(size_t)grow * T + tp]);
                }
            }
            gridbar(bar, nbpl, p + 1, leaf);
        }
    }
}

// ---------------- prep kernels ----------------
// x interleaved: xI[pos*128 + c*32 + kk] = hi(emb[k=c*16+kk]), +16 = lo
__global__ void embed_split_k(const int* __restrict__ tok, const float* __restrict__ emb,
                              unsigned short* __restrict__ xI)
{
    int idx = blockIdx.x * 256 + threadIdx.x;   // B*T*16 quads
    int pos = idx >> 4, q = idx & 15;
    int c = q >> 2, kk4 = (q & 3) * 4;          // k = q*4 = c*16 + kk4
    int tk = tok[pos];
    float4 v = *(const float4*)(emb + (size_t)tk * V + q * 4);
    ushort4 hh, ll;
    hh.x = bf16_hi(v.x); ll.x = bf16_hi(v.x - bf16_f(hh.x));
    hh.y = bf16_hi(v.y); ll.y = bf16_hi(v.y - bf16_f(hh.y));
    hh.z = bf16_hi(v.z); ll.z = bf16_hi(v.z - bf16_f(hh.z));
    hh.w = bf16_hi(v.w); ll.w = bf16_hi(v.w - bf16_f(hh.w));
    size_t base = (size_t)pos * 128 + c * 32 + kk4;
    *(ushort4*)(xI + base) = hh;
    *(ushort4*)(xI + base + 16) = ll;
}

// weight lo-plane prepack, fragment order (per block ug: [K/8][32][8])
__global__ void wlo_k(const float* __restrict__ Wx, const float* __restrict__ Wh,
                      unsigned short* __restrict__ dst, int K, int Dx)
{
    int idx = blockIdx.x * 256 + threadIdx.x;   // 64 * K * 32
    int ug = idx / (K * 32);
    int rem = idx - ug * (K * 32);
    int k = rem >> 5, n = rem & 31, u = n >> 2, g = n & 3;
    int col = g * 512 + ug * 8 + u;
    float w = (k < Dx) ? Wx[(size_t)k * G4U + col] : Wh[(size_t)(k - Dx) * G4U + col];
    unsigned short hi = bf16_hi(w);
    dst[(size_t)ug * (K * 32) + ((k >> 3) * 32 + n) * 8 + (k & 7)] = bf16_hi(w - bf16_f(hi));
}

__global__ void latent_k(const unsigned short* __restrict__ h2,
                         const float* __restrict__ eps,
                         const float* __restrict__ wm, const float* __restrict__ bm,
                         const float* __restrict__ wsig, const float* __restrict__ bs,
                         float* __restrict__ lat)
{
    __shared__ float hr[U];
    int b = blockIdx.x, l = threadIdx.x;
    {
        size_t o1 = (size_t)b * 1024 + (l >> 4) * 32 + (l & 15);
        int l2 = l + 256;
        size_t o2 = (size_t)b * 1024 + (l2 >> 4) * 32 + (l2 & 15);
        hr[l]  = bf16_f(h2[o1]) + bf16_f(h2[o1 + 16]);
        hr[l2] = bf16_f(h2[o2]) + bf16_f(h2[o2 + 16]);
    }
    __syncthreads();
    float am = bm[l], as = bs[l];
    for (int k = 0; k < U; ++k) {
        float h = hr[k];
        am = fmaf(h, wm[(size_t)k * L + l], am);
        as = fmaf(h, wsig[(size_t)k * L + l], as);
    }
    lat[(size_t)b * L + l] = am + expf(as * 0.5f) * eps[(size_t)b * L + l];
}

// xcr[b][ugi*32+u*4+g] = dec_b0 + latent @ dec_Wx0[0:L]  (col oc = g*512+ugi*8+u)
__global__ void xcr_k(const float* __restrict__ lat, const float* __restrict__ Wx0,
                      const float* __restrict__ b0v, float* __restrict__ xcr)
{
    __shared__ float lr[L];
    int b = blockIdx.x >> 3;
    int oc = (blockIdx.x & 7) * 256 + threadIdx.x;
    lr[threadIdx.x] = lat[(size_t)b * L + threadIdx.x];
    __syncthreads();
    float acc = b0v[oc];
    for (int k = 0; k < L; ++k) acc = fmaf(lr[k], Wx0[(size_t)k * G4U + oc], acc);
    int g = oc >> 9, rest = oc & 511, ugi = rest >> 3, u = rest & 7;
    xcr[(size_t)b * G4U + ugi * 32 + u * 4 + g] = acc;
}

__global__ void biasref_k(const float* s0, const float* s1, const float* s2,
                          const float* s3, const float* s4, float* __restrict__ ebr)
{
    int idx = blockIdx.x * 256 + threadIdx.x;   // 5*2048
    int which = idx >> 11, oc = idx & 2047;
    const float* s = which == 0 ? s0 : which == 1 ? s1 : which == 2 ? s2
                   : which == 3 ? s3 : s4;
    int g = oc >> 9, rest = oc & 511, ugi = rest >> 3, u = rest & 7;
    ebr[which * 2048 + ugi * 32 + u * 4 + g] = s[oc];
}

// Wt[v][k] = dec_W[k][v]  (transposed projection weight, float4-loadable rows)
__global__ void wtprep_k(const float* __restrict__ W, float* __restrict__ Wt)
{
    int idx = blockIdx.x * 256 + threadIdx.x;   // 32768
    int k = idx >> 6, v = idx & 63;
    Wt[(size_t)v * 512 + k] = W[idx];
}

__global__ void barinit_k(int* __restrict__ bar)
{
    bar[threadIdx.x] = 0;   // 160 ints: 8 leaves*16, root@128, gen@144
}

__global__ void sentinel_k(float* __restrict__ out, float val) { out[threadIdx.x] = val; }

extern "C" void kernel_launch(void* const* d_in, const int* in_sizes, int n_in,
                              void* d_out, int out_size, void* d_ws, size_t ws_size,
                              hipStream_t stream)
{
    const int*   tokens   = (const int*)  d_in[0];
    const float* eps      = (const float*)d_in[1];
    const float* emb      = (const float*)d_in[2];
    const float* enc_Wx0  = (const float*)d_in[3];
    const float* enc_Wh0  = (const float*)d_in[4];
    const float* enc_b0   = (const float*)d_in[5];
    const float* enc_Wx12 = (const float*)d_in[6];
    const float* enc_Wh12 = (const float*)d_in[7];
    const float* enc_b12  = (const float*)d_in[8];
    const float* w_mean   = (const float*)d_in[9];
    const float* b_mean   = (const float*)d_in[10];
    const float* w_sigma  = (const float*)d_in[11];
    const float* b_sigma  = (const float*)d_in[12];
    const float* dec_Wx0  = (const float*)d_in[13];
    const float* dec_Wh0  = (const float*)d_in[14];
    const float* dec_b0   = (const float*)d_in[15];
    const float* dec_Wx12 = (const float*)d_in[16];
    const float* dec_Wh12 = (const float*)d_in[17];
    const float* dec_b12  = (const float*)d_in[18];
    const float* dec_W    = (const float*)d_in[19];
    const float* dec_b    = (const float*)d_in[20];
    float* out = (float*)d_out;

    // workspace carve-up (all 16B aligned)
    unsigned short* xI  = (unsigned short*)d_ws;                  // B*T*128 us
    unsigned short* h   = xI + (size_t)B * T * 128;               // 6*HBUF us
    unsigned short* wlo = h + 6 * (size_t)HBUF;                   // WLO_TOTAL us
    float* lat = (float*)(wlo + WLO_TOTAL);                       // B*L
    float* xcr = lat + (size_t)B * L;                             // B*2048
    float* ebr = xcr + (size_t)B * G4U;                           // 5*2048
    float* Wt  = ebr + 5 * G4U;                                   // 64*512
    int*   bar = (int*)(Wt + 64 * 512);                           // 160 ints
    size_t need = (size_t)((char*)(bar + 160) - (char*)d_ws);
    if (ws_size < need) {
        sentinel_k<<<dim3(1), dim3(64), 0, stream>>>(out, -1.0e6f);
        return;
    }

    const size_t UG = (size_t)U * G4U;

    embed_split_k<<<dim3(B * T * 16 / 256), dim3(256), 0, stream>>>(tokens, emb, xI);
    biasref_k<<<dim3(40), dim3(256), 0, stream>>>(enc_b0, enc_b12, enc_b12 + G4U,
                                                  dec_b12, dec_b12 + G4U, ebr);
    wtprep_k<<<dim3(128), dim3(256), 0, stream>>>(dec_W, Wt);

    auto coop = [&](int grid, const float* Wx0_, const float* Wh0_,
                    const float* Wx1_, const float* Wh1_,
                    const float* Wx2_, const float* Wh2_,
                    const float* cbb, const float* rb,
                    const float* pW, const float* pB, int np) -> hipError_t {
        const unsigned short* a_xI = xI;
        const unsigned short* a_wlo = wlo;
        unsigned short* a_h = h;
        float* a_out = out;
        int* a_bar = bar;
        void* args[] = { (void*)&a_xI,
                         (void*)&Wx0_, (void*)&Wh0_, (void*)&Wx1_, (void*)&Wh1_,
                         (void*)&Wx2_, (void*)&Wh2_, (void*)&a_wlo,
                         (void*)&cbb, (void*)&rb, (void*)&a_h,
                         (void*)&pW, (void*)&pB, (void*)&a_out, (void*)&np,
                         (void*)&a_bar };
        return hipLaunchCooperativeKernel((void*)vae_stack, dim3(grid), dim3(512),
                                          args, 0, stream);
    };

    // ---------------- encoder (192 blocks: no projection role) ----------------
    wlo_k<<<dim3(4608), dim3(256), 0, stream>>>(enc_Wx0, enc_Wh0, wlo, 576, 64);
    wlo_k<<<dim3(8192), dim3(256), 0, stream>>>(enc_Wx12, enc_Wh12, wlo + WLO_R1, 1024, 512);
    wlo_k<<<dim3(8192), dim3(256), 0, stream>>>(enc_Wx12 + UG, enc_Wh12 + UG,
                                                wlo + WLO_R2, 1024, 512);
    barinit_k<<<dim3(1), dim3(160), 0, stream>>>(bar);
    hipError_t e1 = coop(192, enc_Wx0, enc_Wh0, enc_Wx12, enc_Wh12,
                         enc_Wx12 + UG, enc_Wh12 + UG,
                         ebr, nullptr, nullptr, nullptr, T + 2);

    // latent head reads encoder h2[t=255] (buf 1): interleaved panel 5
    latent_k<<<dim3(B), dim3(256), 0, stream>>>(h + 5 * (size_t)HBUF,
                                                eps, w_mean, b_mean, w_sigma, b_sigma, lat);
    xcr_k<<<dim3(2048), dim3(256), 0, stream>>>(lat, dec_Wx0, dec_b0, xcr);

    // ---------------- decoder (256 blocks, fused projection) ----------------
    wlo_k<<<dim3(4608), dim3(256), 0, stream>>>(dec_Wx0 + (size_t)L * G4U, dec_Wh0,
                                                wlo, 576, 64);
    wlo_k<<<dim3(8192), dim3(256), 0, stream>>>(dec_Wx12, dec_Wh12, wlo + WLO_R1, 1024, 512);
    wlo_k<<<dim3(8192), dim3(256), 0, stream>>>(dec_Wx12 + UG, dec_Wh12 + UG,
                                                wlo + WLO_R2, 1024, 512);
    barinit_k<<<dim3(1), dim3(160), 0, stream>>>(bar);
    hipError_t e2 = coop(256, dec_Wx0 + (size_t)L * G4U, dec_Wh0, dec_Wx12, dec_Wh12,
                         dec_Wx12 + UG, dec_Wh12 + UG,
                         ebr + 2 * G4U, xcr, Wt, dec_b, T + 3);

    if (e1 != hipSuccess || e2 != hipSuccess) {
        sentinel_k<<<dim3(1), dim3(64), 0, stream>>>(out, -3.0e6f);
    }
}

// Round 9
// 22804.437 us; speedup vs baseline: 8.9101x; 1.1882x over previous
//
#include <hip/hip_runtime.h>
#include <math.h>

#define B 256
#define T 256
#define U 512
#define L 256
#define V 64
#define G4U 2048
#define BU (B * U)
#define HBUF 262144   // ushorts per (layer,buf) interleaved h panel: 256 rows * 1024

typedef __attribute__((ext_vector_type(8))) short bf16x8;
typedef __attribute__((ext_vector_type(16))) float f32x16;

__device__ __forceinline__ unsigned short bf16_hi(float x) {
    union { float f; unsigned int u; } c; c.f = x;
    unsigned int r = c.u + 0x7fffu + ((c.u >> 16) & 1u);   // RNE
    return (unsigned short)(r >> 16);
}
__device__ __forceinline__ float bf16_f(unsigned short h) {
    union { unsigned int u; float f; } c; c.u = ((unsigned int)h) << 16;
    return c.f;
}

// Grid barrier: per-block release flag + master scan + gen publish. AGENT scope.
// Arrival is one parallel store per block (no RMW serialization). Chain:
// producer rel-store flags[bid] -> master acq-load -> master rel-store gen ->
// consumer acq-load gen. Per-wave vmcnt(0) orders ALL waves' stores (not just
// thread 0's) before the block's flag is raised.
__device__ __forceinline__ void gridbar(int* bar, int nb, int ph, int bid)
{
    asm volatile("s_waitcnt vmcnt(0)" ::: "memory");   // each wave's stores done
    __syncthreads();
    const int target = ph + 1;
    const int tid = threadIdx.x;
    if (tid == 0)
        __hip_atomic_store(&bar[bid], target, __ATOMIC_RELEASE,
                           __HIP_MEMORY_SCOPE_AGENT);
    if (bid == 0 && tid < 64) {           // master = block 0, wave 0
        bool ok;
        do {
            ok = true;
            for (int i = tid; i < nb; i += 64)
                ok &= (__hip_atomic_load(&bar[i], __ATOMIC_RELAXED,
                                         __HIP_MEMORY_SCOPE_AGENT) >= target);
        } while (!__all(ok));
        for (int i = tid; i < nb; i += 64)   // acquire pass anchors the chain
            (void)__hip_atomic_load(&bar[i], __ATOMIC_ACQUIRE,
                                    __HIP_MEMORY_SCOPE_AGENT);
        if (tid == 0)
            __hip_atomic_store(&bar[320], target, __ATOMIC_RELEASE,
                               __HIP_MEMORY_SCOPE_AGENT);
    }
    if (tid == 0) {
        while (__hip_atomic_load(&bar[320], __ATOMIC_RELAXED,
                                 __HIP_MEMORY_SCOPE_AGENT) < target)
            __builtin_amdgcn_s_sleep(1);
        (void)__hip_atomic_load(&bar[320], __ATOMIC_ACQUIRE,
                                __HIP_MEMORY_SCOPE_AGENT);
    }
    __syncthreads();
}

// Simple 4-chunk GEMM (role0 x-part): 8 A-loads then 12 MFMAs. B from LDS.
__device__ __forceinline__ void gemm4(const unsigned short* __restrict__ abase,
                                      const unsigned short* bhiB,
                                      const unsigned short* bloB,
                                      int kh8, f32x16& acc)
{
    bf16x8 ah[4], al[4];
    #pragma unroll
    for (int i = 0; i < 4; ++i) {
        ah[i] = *(const bf16x8*)(abase + i * 32 + kh8);
        al[i] = *(const bf16x8*)(abase + i * 32 + 16 + kh8);
    }
    #pragma unroll
    for (int i = 0; i < 4; ++i) {
        bf16x8 bh = *(const bf16x8*)(bhiB + i * 512);
        bf16x8 bl = *(const bf16x8*)(bloB + i * 512);
        acc = __builtin_amdgcn_mfma_f32_32x32x16_bf16(ah[i], bh, acc, 0, 0, 0);
        acc = __builtin_amdgcn_mfma_f32_32x32x16_bf16(ah[i], bl, acc, 0, 0, 0);
        acc = __builtin_amdgcn_mfma_f32_32x32x16_bf16(al[i], bh, acc, 0, 0, 0);
    }
}

// Software-pipelined GEMM over NCH 16-k chunks, batch=8 (16 A-loads in flight).
// B fragments come from LDS (hi and lo planes), A from global/LLC.
template<int NCH>
__device__ __forceinline__ void gemm_sub(const unsigned short* __restrict__ abase,
                                         const unsigned short* bhiB,
                                         const unsigned short* bloB,
                                         int kh8, f32x16& acc)
{
    constexpr int NB = NCH / 8;
    bf16x8 ah[2][8], al[2][8];
    #pragma unroll
    for (int i = 0; i < 8; ++i) {
        ah[0][i] = *(const bf16x8*)(abase + i * 32 + kh8);
        al[0][i] = *(const bf16x8*)(abase + i * 32 + 16 + kh8);
    }
    #pragma unroll
    for (int b = 0; b < NB; ++b) {
        const int cur = b & 1, nxt = cur ^ 1;
        if (b + 1 < NB) {
            #pragma unroll
            for (int i = 0; i < 8; ++i) {
                const int c = (b + 1) * 8 + i;
                ah[nxt][i] = *(const bf16x8*)(abase + c * 32 + kh8);
                al[nxt][i] = *(const bf16x8*)(abase + c * 32 + 16 + kh8);
            }
        }
        #pragma unroll
        for (int i = 0; i < 8; ++i) {
            const int c = b * 8 + i;
            bf16x8 bh = *(const bf16x8*)(bhiB + c * 512);
            bf16x8 bl = *(const bf16x8*)(bloB + c * 512);
            acc = __builtin_amdgcn_mfma_f32_32x32x16_bf16(ah[cur][i], bh, acc, 0, 0, 0);
            acc = __builtin_amdgcn_mfma_f32_32x32x16_bf16(ah[cur][i], bl, acc, 0, 0, 0);
            acc = __builtin_amdgcn_mfma_f32_32x32x16_bf16(al[cur][i], bh, acc, 0, 0, 0);
        }
    }
}

// Fused 3-layer LSTM stack, diagonal-pipelined, split-bf16 MFMA.
// Blocks 0-63: layer0; 64-127: layer1; 128-191: layer2; 192-255: projection
// (decoder only; encoder launches 192 blocks).
// LDS 128KB static: Whi (lower 64KB) + Wlo (upper 64KB) — both weight planes
// LDS-resident; zero per-phase weight traffic.
__global__ void __launch_bounds__(512, 1)
vae_stack(const unsigned short* __restrict__ xI,
          const float* __restrict__ Wx0, const float* __restrict__ Wh0,
          const float* __restrict__ Wx1, const float* __restrict__ Wh1,
          const float* __restrict__ Wx2, const float* __restrict__ Wh2,
          const float* __restrict__ cb_base, const float* __restrict__ rb0,
          unsigned short* __restrict__ h,
          const float* __restrict__ projW, const float* __restrict__ projB,
          float* __restrict__ out, int nphase, int* __restrict__ bar)
{
    __shared__ __align__(16) char smem[131072];
    const int nb = gridDim.x;
    const int tid = threadIdx.x;
    const int bid = blockIdx.x;
    const int role = bid >> 6;
    const int ug = bid & 63;
    const int lane = tid & 63;
    const int wv = tid >> 6;        // wave id
    const int m0 = wv * 32;

    // zero all h buffers (6 interleaved panels = 786432 uints), grid-stride
    {
        unsigned int* hz = (unsigned int*)h;
        const int stride = nb * 512;
        for (int i = bid * 512 + tid; i < 786432; i += stride)
            __builtin_nontemporal_store(0u, hz + i);
    }

    auto HP = [&](int layer, int buf) -> unsigned short* {
        return h + (size_t)(layer * 2 + buf) * HBUF;
    };

    if (role < 3) {
        const int K  = (role == 0) ? 576 : 1024;
        const int Dx = (role == 0) ? 64 : 512;
        unsigned short* Whi = (unsigned short*)smem;             // lower 64KB
        unsigned short* Wlo = (unsigned short*)(smem + 65536);   // upper 64KB

        // one-time weight stage, both planes (col slot n = u*4+g; col = g*512+ug*8+u)
        const float* WxL = (role == 0) ? Wx0 : ((role == 1) ? Wx1 : Wx2);
        const float* WhL = (role == 0) ? Wh0 : ((role == 1) ? Wh1 : Wh2);
        for (int idx = tid; idx < K * 32; idx += 512) {
            int k = idx >> 5, n = idx & 31, u = n >> 2, g = n & 3;
            int col = g * 512 + ug * 8 + u;
            float w = (k < Dx) ? WxL[(size_t)k * G4U + col]
                               : WhL[(size_t)(k - Dx) * G4U + col];
            unsigned short hi = bf16_hi(w);
            int off = ((k >> 3) * 32 + n) * 8 + (k & 7);
            Whi[off] = hi;
            Wlo[off] = bf16_hi(w - bf16_f(hi));
        }

        const bool userb = (role == 0) && (rb0 != nullptr);
        const float colbias = userb ? 0.0f
                            : cb_base[role * 2048 + ug * 32 + (lane & 31)];
        float cst[16];
        #pragma unroll
        for (int i = 0; i < 16; ++i) cst[i] = 0.0f;

        const int arow = m0 + (lane & 31);      // A row (batch)
        const int kh8  = (lane >> 5) * 8;       // k-half offset in 16-chunk
        const int frg  = (lane >> 5) * 256 + (lane & 31) * 8;  // B frag offset

        gridbar(bar, nb, 0, bid);

        for (int p = 0; p < nphase; ++p) {
            const int t = p - role;
            if (t >= 0 && t < T) {
                const int wr = t & 1, rd = wr ^ 1;
                f32x16 acc;
                #pragma unroll
                for (int i = 0; i < 16; ++i) acc[i] = 0.0f;

                if (role == 0) {
                    gemm4(xI + ((size_t)arow * T + t) * 128,
                          Whi + frg, Wlo + frg, kh8, acc);
                    gemm_sub<32>(HP(0, rd) + (size_t)arow * 1024,
                                 Whi + 4 * 512 + frg, Wlo + 4 * 512 + frg, kh8, acc);
                } else {
                    gemm_sub<32>(HP(role - 1, wr) + (size_t)arow * 1024,
                                 Whi + frg, Wlo + frg, kh8, acc);
                    gemm_sub<32>(HP(role, rd) + (size_t)arow * 1024,
                                 Whi + 32 * 512 + frg, Wlo + 32 * 512 + frg, kh8, acc);
                }

                // pointwise: C layout col=lane&31, row=(r&3)+8*(r>>2)+4*(lane>>5)
                const int n = lane & 31, g = n & 3, u8 = n >> 2, hi5 = lane >> 5;
                unsigned short* hw = HP(role, wr);
                const int gu = ug * 8 + u8;
                const int guo = (gu >> 4) * 32 + (gu & 15);   // interleaved offset
                const bool g1 = (g & 1), g2 = (g & 2);
                #pragma unroll
                for (int r = 0; r < 16; ++r) {
                    int grow = m0 + (r & 3) + 8 * (r >> 2) + 4 * hi5;
                    float z = acc[r] + colbias;
                    if (userb) z += rb0[(size_t)grow * G4U + ug * 32 + n];
                    float zb = __shfl_xor(z, 1, 64);
                    float zc = __shfl_xor(z, 2, 64);
                    float zd = __shfl_xor(z, 3, 64);
                    float t01 = g1 ? zb : z,  t23 = g1 ? zd : zc;
                    float u01 = g1 ? z  : zb, u23 = g1 ? zc : zd;
                    float zi = g2 ? t23 : t01;
                    float zf = g2 ? u23 : u01;
                    float zG = g2 ? t01 : t23;
                    float zo = g2 ? u01 : u23;
                    float ig = 1.0f / (1.0f + expf(-zi));
                    float fg = 1.0f / (1.0f + expf(-zf));
                    float gg = tanhf(zG);
                    float og = 1.0f / (1.0f + expf(-zo));
                    cst[r] = fg * cst[r] + ig * gg;
                    float hv = og * tanhf(cst[r]);
                    if (g == 0) {
                        unsigned short hh2 = bf16_hi(hv);
                        unsigned short hl2 = bf16_hi(hv - bf16_f(hh2));
                        size_t ho = (size_t)grow * 1024 + guo;
                        __builtin_nontemporal_store(hh2, hw + ho);
                        __builtin_nontemporal_store(hl2, hw + ho + 16);
                    }
                }
            }
            gridbar(bar, nb, p + 1, bid);
        }
    } else {
        // ---------------- projection + argmax (decoder only) ----------------
        float* hrow  = (float*)smem;            // [4][512]
        float* parts = (float*)(smem + 8192);   // [256]
        const int b0p = ug * 4;
        const float pbv = projW ? projB[lane] : 0.0f;
        const int r = wv & 3, kp = wv >> 2, v = lane;
        gridbar(bar, nb, 0, bid);
        for (int p = 0; p < nphase; ++p) {
            const int tp = p - 3;
            if (projW && tp >= 0 && tp < T) {
                {   // stage 4 h2 rows (hi+lo recon) into LDS
                    int rr = tid >> 7, kq = (tid & 127) * 4;   // 4 units, same chunk
                    const unsigned short* hb2 = HP(2, tp & 1)
                        + (size_t)(b0p + rr) * 1024 + (kq >> 4) * 32 + (kq & 15);
                    ushort4 vh = *(const ushort4*)hb2;
                    ushort4 vl = *(const ushort4*)(hb2 + 16);
                    float4 f;
                    f.x = bf16_f(vh.x) + bf16_f(vl.x);
                    f.y = bf16_f(vh.y) + bf16_f(vl.y);
                    f.z = bf16_f(vh.z) + bf16_f(vl.z);
                    f.w = bf16_f(vh.w) + bf16_f(vl.w);
                    *(float4*)(hrow + rr * 512 + kq) = f;
                }
                __syncthreads();
                // wave w: r=w&3 (batch row), kp=w>>2 (k half); lane = vocab v.
                float acc = 0.0f;
                const float* wp = projW + (size_t)v * 512 + kp * 256;
                const float* hp = hrow + r * 512 + kp * 256;
                #pragma unroll 8
                for (int q = 0; q < 64; ++q) {
                    float4 w  = *(const float4*)(wp + q * 4);
                    float4 hq = *(const float4*)(hp + q * 4);
                    acc = fmaf(w.x, hq.x, acc); acc = fmaf(w.y, hq.y, acc);
                    acc = fmaf(w.z, hq.z, acc); acc = fmaf(w.w, hq.w, acc);
                }
                if (kp == 1) parts[r * 64 + v] = acc;
                __syncthreads();
                if (kp == 0) {
                    float logit = acc + parts[r * 64 + v] + pbv;
                    int grow = b0p + r;
                    __builtin_nontemporal_store(
                        logit, &out[(size_t)B * T + ((size_t)grow * T + tp) * V + v]);
                    float best = logit; int bi = v;
                    #pragma unroll
                    for (int off = 32; off; off >>= 1) {
                        float ov = __shfl_xor(best, off, 64);
                        int oi  = __shfl_xor(bi, off, 64);
                        if (ov > best || (ov == best && oi < bi)) { best = ov; bi = oi; }
                    }
                    if (v == 0)
                        __builtin_nontemporal_store((float)bi,
                                                    &out[(size_t)grow * T + tp]);
                }
            }
            gridbar(bar, nb, p + 1, bid);
        }
    }
}

// ---------------- prep kernels ----------------
// x interleaved: xI[pos*128 + c*32 + kk] = hi(emb[k=c*16+kk]), +16 = lo
__global__ void embed_split_k(const int* __restrict__ tok, const float* __restrict__ emb,
                              unsigned short* __restrict__ xI)
{
    int idx = blockIdx.x * 256 + threadIdx.x;   // B*T*16 quads
    int pos = idx >> 4, q = idx & 15;
    int c = q >> 2, kk4 = (q & 3) * 4;          // k = q*4 = c*16 + kk4
    int tk = tok[pos];
    float4 v = *(const float4*)(emb + (size_t)tk * V + q * 4);
    ushort4 hh, ll;
    hh.x = bf16_hi(v.x); ll.x = bf16_hi(v.x - bf16_f(hh.x));
    hh.y = bf16_hi(v.y); ll.y = bf16_hi(v.y - bf16_f(hh.y));
    hh.z = bf16_hi(v.z); ll.z = bf16_hi(v.z - bf16_f(hh.z));
    hh.w = bf16_hi(v.w); ll.w = bf16_hi(v.w - bf16_f(hh.w));
    size_t base = (size_t)pos * 128 + c * 32 + kk4;
    *(ushort4*)(xI + base) = hh;
    *(ushort4*)(xI + base + 16) = ll;
}

__global__ void latent_k(const unsigned short* __restrict__ h2,
                         const float* __restrict__ eps,
                         const float* __restrict__ wm, const float* __restrict__ bm,
                         const float* __restrict__ wsig, const float* __restrict__ bs,
                         float* __restrict__ lat)
{
    __shared__ float hr[U];
    int b = blockIdx.x, l = threadIdx.x;
    {
        size_t o1 = (size_t)b * 1024 + (l >> 4) * 32 + (l & 15);
        int l2 = l + 256;
        size_t o2 = (size_t)b * 1024 + (l2 >> 4) * 32 + (l2 & 15);
        hr[l]  = bf16_f(h2[o1]) + bf16_f(h2[o1 + 16]);
        hr[l2] = bf16_f(h2[o2]) + bf16_f(h2[o2 + 16]);
    }
    __syncthreads();
    float am = bm[l], as = bs[l];
    for (int k = 0; k < U; ++k) {
        float h = hr[k];
        am = fmaf(h, wm[(size_t)k * L + l], am);
        as = fmaf(h, wsig[(size_t)k * L + l], as);
    }
    lat[(size_t)b * L + l] = am + expf(as * 0.5f) * eps[(size_t)b * L + l];
}

// xcr[b][ugi*32+u*4+g] = dec_b0 + latent @ dec_Wx0[0:L]  (col oc = g*512+ugi*8+u)
__global__ void xcr_k(const float* __restrict__ lat, const float* __restrict__ Wx0,
                      const float* __restrict__ b0v, float* __restrict__ xcr)
{
    __shared__ float lr[L];
    int b = blockIdx.x >> 3;
    int oc = (blockIdx.x & 7) * 256 + threadIdx.x;
    lr[threadIdx.x] = lat[(size_t)b * L + threadIdx.x];
    __syncthreads();
    float acc = b0v[oc];
    for (int k = 0; k < L; ++k) acc = fmaf(lr[k], Wx0[(size_t)k * G4U + oc], acc);
    int g = oc >> 9, rest = oc & 511, ugi = rest >> 3, u = rest & 7;
    xcr[(size_t)b * G4U + ugi * 32 + u * 4 + g] = acc;
}

__global__ void biasref_k(const float* s0, const float* s1, const float* s2,
                          const float* s3, const float* s4, float* __restrict__ ebr)
{
    int idx = blockIdx.x * 256 + threadIdx.x;   // 5*2048
    int which = idx >> 11, oc = idx & 2047;
    const float* s = which == 0 ? s0 : which == 1 ? s1 : which == 2 ? s2
                   : which == 3 ? s3 : s4;
    int g = oc >> 9, rest = oc & 511, ugi = rest >> 3, u = rest & 7;
    ebr[which * 2048 + ugi * 32 + u * 4 + g] = s[oc];
}

// Wt[v][k] = dec_W[k][v]  (transposed projection weight, float4-loadable rows)
__global__ void wtprep_k(const float* __restrict__ W, float* __restrict__ Wt)
{
    int idx = blockIdx.x * 256 + threadIdx.x;   // 32768
    int k = idx >> 6, v = idx & 63;
    Wt[(size_t)v * 512 + k] = W[idx];
}

__global__ void barinit_k(int* __restrict__ bar)
{
    bar[threadIdx.x] = 0;   // 384 ints: flags[0..255], gen at [320]
}

__global__ void sentinel_k(float* __restrict__ out, float val) { out[threadIdx.x] = val; }

extern "C" void kernel_launch(void* const* d_in, const int* in_sizes, int n_in,
                              void* d_out, int out_size, void* d_ws, size_t ws_size,
                              hipStream_t stream)
{
    const int*   tokens   = (const int*)  d_in[0];
    const float* eps      = (const float*)d_in[1];
    const float* emb      = (const float*)d_in[2];
    const float* enc_Wx0  = (const float*)d_in[3];
    const float* enc_Wh0  = (const float*)d_in[4];
    const float* enc_b0   = (const float*)d_in[5];
    const float* enc_Wx12 = (const float*)d_in[6];
    const float* enc_Wh12 = (const float*)d_in[7];
    const float* enc_b12  = (const float*)d_in[8];
    const float* w_mean   = (const float*)d_in[9];
    const float* b_mean   = (const float*)d_in[10];
    const float* w_sigma  = (const float*)d_in[11];
    const float* b_sigma  = (const float*)d_in[12];
    const float* dec_Wx0  = (const float*)d_in[13];
    const float* dec_Wh0  = (const float*)d_in[14];
    const float* dec_b0   = (const float*)d_in[15];
    const float* dec_Wx12 = (const float*)d_in[16];
    const float* dec_Wh12 = (const float*)d_in[17];
    const float* dec_b12  = (const float*)d_in[18];
    const float* dec_W    = (const float*)d_in[19];
    const float* dec_b    = (const float*)d_in[20];
    float* out = (float*)d_out;

    // workspace carve-up (all 16B aligned)
    unsigned short* xI  = (unsigned short*)d_ws;                  // B*T*128 us
    unsigned short* h   = xI + (size_t)B * T * 128;               // 6*HBUF us
    float* lat = (float*)(h + 6 * (size_t)HBUF);                  // B*L
    float* xcr = lat + (size_t)B * L;                             // B*2048
    float* ebr = xcr + (size_t)B * G4U;                           // 5*2048
    float* Wt  = ebr + 5 * G4U;                                   // 64*512
    int*   bar = (int*)(Wt + 64 * 512);                           // 384 ints
    size_t need = (size_t)((char*)(bar + 384) - (char*)d_ws);
    if (ws_size < need) {
        sentinel_k<<<dim3(1), dim3(64), 0, stream>>>(out, -1.0e6f);
        return;
    }

    const size_t UG = (size_t)U * G4U;

    embed_split_k<<<dim3(B * T * 16 / 256), dim3(256), 0, stream>>>(tokens, emb, xI);
    biasref_k<<<dim3(40), dim3(256), 0, stream>>>(enc_b0, enc_b12, enc_b12 + G4U,
                                                  dec_b12, dec_b12 + G4U, ebr);
    wtprep_k<<<dim3(128), dim3(256), 0, stream>>>(dec_W, Wt);

    auto coop = [&](int grid, const float* Wx0_, const float* Wh0_,
                    const float* Wx1_, const float* Wh1_,
                    const float* Wx2_, const float* Wh2_,
                    const float* cbb, const float* rb,
                    const float* pW, const float* pB, int np) -> hipError_t {
        const unsigned short* a_xI = xI;
        unsigned short* a_h = h;
        float* a_out = out;
        int* a_bar = bar;
        void* args[] = { (void*)&a_xI,
                         (void*)&Wx0_, (void*)&Wh0_, (void*)&Wx1_, (void*)&Wh1_,
                         (void*)&Wx2_, (void*)&Wh2_,
                         (void*)&cbb, (void*)&rb, (void*)&a_h,
                         (void*)&pW, (void*)&pB, (void*)&a_out, (void*)&np,
                         (void*)&a_bar };
        return hipLaunchCooperativeKernel((void*)vae_stack, dim3(grid), dim3(512),
                                          args, 0, stream);
    };

    // ---------------- encoder (192 blocks: no projection role) --------------
    barinit_k<<<dim3(1), dim3(384), 0, stream>>>(bar);
    hipError_t e1 = coop(192, enc_Wx0, enc_Wh0, enc_Wx12, enc_Wh12,
                         enc_Wx12 + UG, enc_Wh12 + UG,
                         ebr, nullptr, nullptr, nullptr, T + 2);

    // latent head reads encoder h2[t=255] (buf 1): interleaved panel 5
    latent_k<<<dim3(B), dim3(256), 0, stream>>>(h + 5 * (size_t)HBUF,
                                                eps, w_mean, b_mean, w_sigma, b_sigma, lat);
    xcr_k<<<dim3(2048), dim3(256), 0, stream>>>(lat, dec_Wx0, dec_b0, xcr);

    // ---------------- decoder (256 blocks, fused projection) ----------------
    barinit_k<<<dim3(1), dim3(384), 0, stream>>>(bar);
    hipError_t e2 = coop(256, dec_Wx0 + (size_t)L * G4U, dec_Wh0, dec_Wx12, dec_Wh12,
                         dec_Wx12 + UG, dec_Wh12 + UG,
                         ebr + 2 * G4U, xcr, Wt, dec_b, T + 3);

    if (e1 != hipSuccess || e2 != hipSuccess) {
        sentinel_k<<<dim3(1), dim3(64), 0, stream>>>(out, -3.0e6f);
    }
}

// Round 10
// 22688.097 us; speedup vs baseline: 8.9558x; 1.0051x over previous
//
#include <hip/hip_runtime.h>
#include <math.h>

#define B 256
#define T 256
#define U 512
#define L 256
#define V 64
#define G4U 2048
#define BU (B * U)
#define HBUF 262144   // ushorts per (layer,buf) interleaved h panel: 256 rows * 1024

typedef __attribute__((ext_vector_type(8))) short bf16x8;
typedef __attribute__((ext_vector_type(16))) float f32x16;

__device__ __forceinline__ unsigned short bf16_hi(float x) {
    union { float f; unsigned int u; } c; c.f = x;
    unsigned int r = c.u + 0x7fffu + ((c.u >> 16) & 1u);   // RNE
    return (unsigned short)(r >> 16);
}
__device__ __forceinline__ float bf16_f(unsigned short h) {
    union { unsigned int u; float f; } c; c.u = ((unsigned int)h) << 16;
    return c.f;
}

// ---- point-to-point role-group flag sync --------------------------------
// flag[bid] lives at bar[bid*16] (own 64B line; no store contention).
// Monotonic: 1 = init done; p+2 = phase p done. Consumers poll one flag per
// lane (wave 0, divergent spin) for each needed role group, then per-flag
// acquire anchors the release chain from that producer.
__device__ __forceinline__ void flags_wait(int* bar, int wmask, int target, int lane)
{
    if (threadIdx.x < 64) {
        #pragma unroll
        for (int r = 0; r < 4; ++r) {
            if (wmask & (1 << r)) {
                const int fi = (r * 64 + lane) * 16;
                while (__hip_atomic_load(&bar[fi], __ATOMIC_RELAXED,
                                         __HIP_MEMORY_SCOPE_AGENT) < target)
                    __builtin_amdgcn_s_sleep(1);
                (void)__hip_atomic_load(&bar[fi], __ATOMIC_ACQUIRE,
                                        __HIP_MEMORY_SCOPE_AGENT);
            }
        }
    }
    __syncthreads();
}
__device__ __forceinline__ void flags_pub(int* bar, int bid, int val)
{
    asm volatile("s_waitcnt vmcnt(0)" ::: "memory");   // each wave's stores done
    __syncthreads();
    if (threadIdx.x == 0)
        __hip_atomic_store(&bar[bid * 16], val, __ATOMIC_RELEASE,
                           __HIP_MEMORY_SCOPE_AGENT);
}

// Simple 4-chunk GEMM (role0 x-part): 8 A-loads then 12 MFMAs. B from LDS.
__device__ __forceinline__ void gemm4(const unsigned short* __restrict__ abase,
                                      const unsigned short* bhiB,
                                      const unsigned short* bloB,
                                      int kh8, f32x16& acc)
{
    bf16x8 ah[4], al[4];
    #pragma unroll
    for (int i = 0; i < 4; ++i) {
        ah[i] = *(const bf16x8*)(abase + i * 32 + kh8);
        al[i] = *(const bf16x8*)(abase + i * 32 + 16 + kh8);
    }
    #pragma unroll
    for (int i = 0; i < 4; ++i) {
        bf16x8 bh = *(const bf16x8*)(bhiB + i * 512);
        bf16x8 bl = *(const bf16x8*)(bloB + i * 512);
        acc = __builtin_amdgcn_mfma_f32_32x32x16_bf16(ah[i], bh, acc, 0, 0, 0);
        acc = __builtin_amdgcn_mfma_f32_32x32x16_bf16(ah[i], bl, acc, 0, 0, 0);
        acc = __builtin_amdgcn_mfma_f32_32x32x16_bf16(al[i], bh, acc, 0, 0, 0);
    }
}

// Software-pipelined GEMM over NCH 16-k chunks, batch=8 (16 A-loads in flight).
template<int NCH>
__device__ __forceinline__ void gemm_sub(const unsigned short* __restrict__ abase,
                                         const unsigned short* bhiB,
                                         const unsigned short* bloB,
                                         int kh8, f32x16& acc)
{
    constexpr int NB = NCH / 8;
    bf16x8 ah[2][8], al[2][8];
    #pragma unroll
    for (int i = 0; i < 8; ++i) {
        ah[0][i] = *(const bf16x8*)(abase + i * 32 + kh8);
        al[0][i] = *(const bf16x8*)(abase + i * 32 + 16 + kh8);
    }
    #pragma unroll
    for (int b = 0; b < NB; ++b) {
        const int cur = b & 1, nxt = cur ^ 1;
        if (b + 1 < NB) {
            #pragma unroll
            for (int i = 0; i < 8; ++i) {
                const int c = (b + 1) * 8 + i;
                ah[nxt][i] = *(const bf16x8*)(abase + c * 32 + kh8);
                al[nxt][i] = *(const bf16x8*)(abase + c * 32 + 16 + kh8);
            }
        }
        #pragma unroll
        for (int i = 0; i < 8; ++i) {
            const int c = b * 8 + i;
            bf16x8 bh = *(const bf16x8*)(bhiB + c * 512);
            bf16x8 bl = *(const bf16x8*)(bloB + c * 512);
            acc = __builtin_amdgcn_mfma_f32_32x32x16_bf16(ah[cur][i], bh, acc, 0, 0, 0);
            acc = __builtin_amdgcn_mfma_f32_32x32x16_bf16(ah[cur][i], bl, acc, 0, 0, 0);
            acc = __builtin_amdgcn_mfma_f32_32x32x16_bf16(al[cur][i], bh, acc, 0, 0, 0);
        }
    }
}

// Fused 3-layer LSTM stack, diagonal-pipelined, split-bf16 MFMA.
// Blocks 0-63: layer0; 64-127: layer1; 128-191: layer2; 192-255: projection
// (decoder only; encoder launches 192 blocks).
// LDS 128KB static: Whi + Wlo (both weight planes LDS-resident).
// Sync: point-to-point role-group flags (deps = adjacent roles only).
__global__ void __launch_bounds__(512, 1)
vae_stack(const unsigned short* __restrict__ xI,
          const float* __restrict__ Wx0, const float* __restrict__ Wh0,
          const float* __restrict__ Wx1, const float* __restrict__ Wh1,
          const float* __restrict__ Wx2, const float* __restrict__ Wh2,
          const float* __restrict__ cb_base, const float* __restrict__ rb0,
          unsigned short* __restrict__ h,
          const float* __restrict__ projW, const float* __restrict__ projB,
          float* __restrict__ out, int nphase, int* __restrict__ bar)
{
    __shared__ __align__(16) char smem[131072];
    const int nb = gridDim.x;
    const int tid = threadIdx.x;
    const int bid = blockIdx.x;
    const int role = bid >> 6;
    const int ug = bid & 63;
    const int lane = tid & 63;
    const int wv = tid >> 6;        // wave id
    const int m0 = wv * 32;

    // role dependence masks: {r-1 producer, r own-prev, r+1 WAR}
    const int allmask = (nb == 256) ? 0b1111 : 0b0111;
    int wmask;
    if      (role == 0) wmask = 0b0011;
    else if (role == 1) wmask = 0b0111;
    else if (role == 2) wmask = (nb == 256) ? 0b1110 : 0b0110;
    else                wmask = 0b0100;

    // zero all h buffers (6 interleaved panels = 786432 uints), grid-stride
    {
        unsigned int* hz = (unsigned int*)h;
        const int stride = nb * 512;
        for (int i = bid * 512 + tid; i < 786432; i += stride)
            __builtin_nontemporal_store(0u, hz + i);
    }

    auto HP = [&](int layer, int buf) -> unsigned short* {
        return h + (size_t)(layer * 2 + buf) * HBUF;
    };

    if (role < 3) {
        const int K  = (role == 0) ? 576 : 1024;
        const int Dx = (role == 0) ? 64 : 512;
        unsigned short* Whi = (unsigned short*)smem;             // lower 64KB
        unsigned short* Wlo = (unsigned short*)(smem + 65536);   // upper 64KB

        // one-time weight stage, both planes (col slot n = u*4+g; col = g*512+ug*8+u)
        const float* WxL = (role == 0) ? Wx0 : ((role == 1) ? Wx1 : Wx2);
        const float* WhL = (role == 0) ? Wh0 : ((role == 1) ? Wh1 : Wh2);
        for (int idx = tid; idx < K * 32; idx += 512) {
            int k = idx >> 5, n = idx & 31, u = n >> 2, g = n & 3;
            int col = g * 512 + ug * 8 + u;
            float w = (k < Dx) ? WxL[(size_t)k * G4U + col]
                               : WhL[(size_t)(k - Dx) * G4U + col];
            unsigned short hi = bf16_hi(w);
            int off = ((k >> 3) * 32 + n) * 8 + (k & 7);
            Whi[off] = hi;
            Wlo[off] = bf16_hi(w - bf16_f(hi));
        }

        const bool userb = (role == 0) && (rb0 != nullptr);
        const float colbias = userb ? 0.0f
                            : cb_base[role * 2048 + ug * 32 + (lane & 31)];
        float cst[16];
        #pragma unroll
        for (int i = 0; i < 16; ++i) cst[i] = 0.0f;

        const int arow = m0 + (lane & 31);      // A row (batch)
        const int kh8  = (lane >> 5) * 8;       // k-half offset in 16-chunk
        const int frg  = (lane >> 5) * 256 + (lane & 31) * 8;  // B frag offset

        // init rendezvous: ALL blocks zeroed h slices -> full-grid wait once
        flags_pub(bar, bid, 1);
        flags_wait(bar, allmask, 1, lane);

        for (int p = 0; p < nphase; ++p) {
            flags_wait(bar, wmask, p + 1, lane);   // deps finished phase p-1
            const int t = p - role;
            if (t >= 0 && t < T) {
                const int wr = t & 1, rd = wr ^ 1;
                f32x16 acc;
                #pragma unroll
                for (int i = 0; i < 16; ++i) acc[i] = 0.0f;

                if (role == 0) {
                    gemm4(xI + ((size_t)arow * T + t) * 128,
                          Whi + frg, Wlo + frg, kh8, acc);
                    gemm_sub<32>(HP(0, rd) + (size_t)arow * 1024,
                                 Whi + 4 * 512 + frg, Wlo + 4 * 512 + frg, kh8, acc);
                } else {
                    gemm_sub<32>(HP(role - 1, wr) + (size_t)arow * 1024,
                                 Whi + frg, Wlo + frg, kh8, acc);
                    gemm_sub<32>(HP(role, rd) + (size_t)arow * 1024,
                                 Whi + 32 * 512 + frg, Wlo + 32 * 512 + frg, kh8, acc);
                }

                // pointwise: C layout col=lane&31, row=(r&3)+8*(r>>2)+4*(lane>>5)
                const int n = lane & 31, g = n & 3, u8 = n >> 2, hi5 = lane >> 5;
                unsigned short* hw = HP(role, wr);
                const int gu = ug * 8 + u8;
                const int guo = (gu >> 4) * 32 + (gu & 15);   // interleaved offset
                const bool g1 = (g & 1), g2 = (g & 2);
                #pragma unroll
                for (int r = 0; r < 16; ++r) {
                    int grow = m0 + (r & 3) + 8 * (r >> 2) + 4 * hi5;
                    float z = acc[r] + colbias;
                    if (userb) z += rb0[(size_t)grow * G4U + ug * 32 + n];
                    float zb = __shfl_xor(z, 1, 64);
                    float zc = __shfl_xor(z, 2, 64);
                    float zd = __shfl_xor(z, 3, 64);
                    float t01 = g1 ? zb : z,  t23 = g1 ? zd : zc;
                    float u01 = g1 ? z  : zb, u23 = g1 ? zc : zd;
                    float zi = g2 ? t23 : t01;
                    float zf = g2 ? u23 : u01;
                    float zG = g2 ? t01 : t23;
                    float zo = g2 ? u01 : u23;
                    float ig = 1.0f / (1.0f + expf(-zi));
                    float fg = 1.0f / (1.0f + expf(-zf));
                    float gg = tanhf(zG);
                    float og = 1.0f / (1.0f + expf(-zo));
                    cst[r] = fg * cst[r] + ig * gg;
                    float hv = og * tanhf(cst[r]);
                    if (g == 0) {
                        unsigned short hh2 = bf16_hi(hv);
                        unsigned short hl2 = bf16_hi(hv - bf16_f(hh2));
                        size_t ho = (size_t)grow * 1024 + guo;
                        __builtin_nontemporal_store(hh2, hw + ho);
                        __builtin_nontemporal_store(hl2, hw + ho + 16);
                    }
                }
            }
            flags_pub(bar, bid, p + 2);
        }
    } else {
        // ---------------- projection + argmax (decoder only) ----------------
        float* hrow  = (float*)smem;            // [4][512]
        float* parts = (float*)(smem + 8192);   // [256]
        const int b0p = ug * 4;
        const float pbv = projW ? projB[lane] : 0.0f;
        const int r = wv & 3, kp = wv >> 2, v = lane;
        flags_pub(bar, bid, 1);
        flags_wait(bar, allmask, 1, lane);
        for (int p = 0; p < nphase; ++p) {
            flags_wait(bar, wmask, p + 1, lane);
            const int tp = p - 3;
            if (projW && tp >= 0 && tp < T) {
                {   // stage 4 h2 rows (hi+lo recon) into LDS
                    int rr = tid >> 7, kq = (tid & 127) * 4;   // 4 units, same chunk
                    const unsigned short* hb2 = HP(2, tp & 1)
                        + (size_t)(b0p + rr) * 1024 + (kq >> 4) * 32 + (kq & 15);
                    ushort4 vh = *(const ushort4*)hb2;
                    ushort4 vl = *(const ushort4*)(hb2 + 16);
                    float4 f;
                    f.x = bf16_f(vh.x) + bf16_f(vl.x);
                    f.y = bf16_f(vh.y) + bf16_f(vl.y);
                    f.z = bf16_f(vh.z) + bf16_f(vl.z);
                    f.w = bf16_f(vh.w) + bf16_f(vl.w);
                    *(float4*)(hrow + rr * 512 + kq) = f;
                }
                __syncthreads();
                // wave w: r=w&3 (batch row), kp=w>>2 (k half); lane = vocab v.
                float acc = 0.0f;
                const float* wp = projW + (size_t)v * 512 + kp * 256;
                const float* hp = hrow + r * 512 + kp * 256;
                #pragma unroll 8
                for (int q = 0; q < 64; ++q) {
                    float4 w  = *(const float4*)(wp + q * 4);
                    float4 hq = *(const float4*)(hp + q * 4);
                    acc = fmaf(w.x, hq.x, acc); acc = fmaf(w.y, hq.y, acc);
                    acc = fmaf(w.z, hq.z, acc); acc = fmaf(w.w, hq.w, acc);
                }
                if (kp == 1) parts[r * 64 + v] = acc;
                __syncthreads();
                if (kp == 0) {
                    float logit = acc + parts[r * 64 + v] + pbv;
                    int grow = b0p + r;
                    __builtin_nontemporal_store(
                        logit, &out[(size_t)B * T + ((size_t)grow * T + tp) * V + v]);
                    float best = logit; int bi = v;
                    #pragma unroll
                    for (int off = 32; off; off >>= 1) {
                        float ov = __shfl_xor(best, off, 64);
                        int oi  = __shfl_xor(bi, off, 64);
                        if (ov > best || (ov == best && oi < bi)) { best = ov; bi = oi; }
                    }
                    if (v == 0)
                        __builtin_nontemporal_store((float)bi,
                                                    &out[(size_t)grow * T + tp]);
                }
            }
            flags_pub(bar, bid, p + 2);
        }
    }
}

// ---------------- prep kernels ----------------
// x interleaved: xI[pos*128 + c*32 + kk] = hi(emb[k=c*16+kk]), +16 = lo
__global__ void embed_split_k(const int* __restrict__ tok, const float* __restrict__ emb,
                              unsigned short* __restrict__ xI)
{
    int idx = blockIdx.x * 256 + threadIdx.x;   // B*T*16 quads
    int pos = idx >> 4, q = idx & 15;
    int c = q >> 2, kk4 = (q & 3) * 4;          // k = q*4 = c*16 + kk4
    int tk = tok[pos];
    float4 v = *(const float4*)(emb + (size_t)tk * V + q * 4);
    ushort4 hh, ll;
    hh.x = bf16_hi(v.x); ll.x = bf16_hi(v.x - bf16_f(hh.x));
    hh.y = bf16_hi(v.y); ll.y = bf16_hi(v.y - bf16_f(hh.y));
    hh.z = bf16_hi(v.z); ll.z = bf16_hi(v.z - bf16_f(hh.z));
    hh.w = bf16_hi(v.w); ll.w = bf16_hi(v.w - bf16_f(hh.w));
    size_t base = (size_t)pos * 128 + c * 32 + kk4;
    *(ushort4*)(xI + base) = hh;
    *(ushort4*)(xI + base + 16) = ll;
}

__global__ void latent_k(const unsigned short* __restrict__ h2,
                         const float* __restrict__ eps,
                         const float* __restrict__ wm, const float* __restrict__ bm,
                         const float* __restrict__ wsig, const float* __restrict__ bs,
                         float* __restrict__ lat)
{
    __shared__ float hr[U];
    int b = blockIdx.x, l = threadIdx.x;
    {
        size_t o1 = (size_t)b * 1024 + (l >> 4) * 32 + (l & 15);
        int l2 = l + 256;
        size_t o2 = (size_t)b * 1024 + (l2 >> 4) * 32 + (l2 & 15);
        hr[l]  = bf16_f(h2[o1]) + bf16_f(h2[o1 + 16]);
        hr[l2] = bf16_f(h2[o2]) + bf16_f(h2[o2 + 16]);
    }
    __syncthreads();
    float am = bm[l], as = bs[l];
    for (int k = 0; k < U; ++k) {
        float h = hr[k];
        am = fmaf(h, wm[(size_t)k * L + l], am);
        as = fmaf(h, wsig[(size_t)k * L + l], as);
    }
    lat[(size_t)b * L + l] = am + expf(as * 0.5f) * eps[(size_t)b * L + l];
}

// xcr[b][ugi*32+u*4+g] = dec_b0 + latent @ dec_Wx0[0:L]  (col oc = g*512+ugi*8+u)
__global__ void xcr_k(const float* __restrict__ lat, const float* __restrict__ Wx0,
                      const float* __restrict__ b0v, float* __restrict__ xcr)
{
    __shared__ float lr[L];
    int b = blockIdx.x >> 3;
    int oc = (blockIdx.x & 7) * 256 + threadIdx.x;
    lr[threadIdx.x] = lat[(size_t)b * L + threadIdx.x];
    __syncthreads();
    float acc = b0v[oc];
    for (int k = 0; k < L; ++k) acc = fmaf(lr[k], Wx0[(size_t)k * G4U + oc], acc);
    int g = oc >> 9, rest = oc & 511, ugi = rest >> 3, u = rest & 7;
    xcr[(size_t)b * G4U + ugi * 32 + u * 4 + g] = acc;
}

__global__ void biasref_k(const float* s0, const float* s1, const float* s2,
                          const float* s3, const float* s4, float* __restrict__ ebr)
{
    int idx = blockIdx.x * 256 + threadIdx.x;   // 5*2048
    int which = idx >> 11, oc = idx & 2047;
    const float* s = which == 0 ? s0 : which == 1 ? s1 : which == 2 ? s2
                   : which == 3 ? s3 : s4;
    int g = oc >> 9, rest = oc & 511, ugi = rest >> 3, u = rest & 7;
    ebr[which * 2048 + ugi * 32 + u * 4 + g] = s[oc];
}

// Wt[v][k] = dec_W[k][v]  (transposed projection weight, float4-loadable rows)
__global__ void wtprep_k(const float* __restrict__ W, float* __restrict__ Wt)
{
    int idx = blockIdx.x * 256 + threadIdx.x;   // 32768
    int k = idx >> 6, v = idx & 63;
    Wt[(size_t)v * 512 + k] = W[idx];
}

__global__ void barinit_k(int* __restrict__ bar)
{
    bar[blockIdx.x * 256 + threadIdx.x] = 0;   // 4096 ints (256 flag lines)
}

__global__ void sentinel_k(float* __restrict__ out, float val) { out[threadIdx.x] = val; }

extern "C" void kernel_launch(void* const* d_in, const int* in_sizes, int n_in,
                              void* d_out, int out_size, void* d_ws, size_t ws_size,
                              hipStream_t stream)
{
    const int*   tokens   = (const int*)  d_in[0];
    const float* eps      = (const float*)d_in[1];
    const float* emb      = (const float*)d_in[2];
    const float* enc_Wx0  = (const float*)d_in[3];
    const float* enc_Wh0  = (const float*)d_in[4];
    const float* enc_b0   = (const float*)d_in[5];
    const float* enc_Wx12 = (const float*)d_in[6];
    const float* enc_Wh12 = (const float*)d_in[7];
    const float* enc_b12  = (const float*)d_in[8];
    const float* w_mean   = (const float*)d_in[9];
    const float* b_mean   = (const float*)d_in[10];
    const float* w_sigma  = (const float*)d_in[11];
    const float* b_sigma  = (const float*)d_in[12];
    const float* dec_Wx0  = (const float*)d_in[13];
    const float* dec_Wh0  = (const float*)d_in[14];
    const float* dec_b0   = (const float*)d_in[15];
    const float* dec_Wx12 = (const float*)d_in[16];
    const float* dec_Wh12 = (const float*)d_in[17];
    const float* dec_b12  = (const float*)d_in[18];
    const float* dec_W    = (const float*)d_in[19];
    const float* dec_b    = (const float*)d_in[20];
    float* out = (float*)d_out;

    // workspace carve-up (all 16B aligned)
    unsigned short* xI  = (unsigned short*)d_ws;                  // B*T*128 us
    unsigned short* h   = xI + (size_t)B * T * 128;               // 6*HBUF us
    float* lat = (float*)(h + 6 * (size_t)HBUF);                  // B*L
    float* xcr = lat + (size_t)B * L;                             // B*2048
    float* ebr = xcr + (size_t)B * G4U;                           // 5*2048
    float* Wt  = ebr + 5 * G4U;                                   // 64*512
    int*   bar = (int*)(Wt + 64 * 512);                           // 4096 ints
    size_t need = (size_t)((char*)(bar + 4096) - (char*)d_ws);
    if (ws_size < need) {
        sentinel_k<<<dim3(1), dim3(64), 0, stream>>>(out, -1.0e6f);
        return;
    }

    const size_t UG = (size_t)U * G4U;

    embed_split_k<<<dim3(B * T * 16 / 256), dim3(256), 0, stream>>>(tokens, emb, xI);
    biasref_k<<<dim3(40), dim3(256), 0, stream>>>(enc_b0, enc_b12, enc_b12 + G4U,
                                                  dec_b12, dec_b12 + G4U, ebr);
    wtprep_k<<<dim3(128), dim3(256), 0, stream>>>(dec_W, Wt);

    auto coop = [&](int grid, const float* Wx0_, const float* Wh0_,
                    const float* Wx1_, const float* Wh1_,
                    const float* Wx2_, const float* Wh2_,
                    const float* cbb, const float* rb,
                    const float* pW, const float* pB, int np) -> hipError_t {
        const unsigned short* a_xI = xI;
        unsigned short* a_h = h;
        float* a_out = out;
        int* a_bar = bar;
        void* args[] = { (void*)&a_xI,
                         (void*)&Wx0_, (void*)&Wh0_, (void*)&Wx1_, (void*)&Wh1_,
                         (void*)&Wx2_, (void*)&Wh2_,
                         (void*)&cbb, (void*)&rb, (void*)&a_h,
                         (void*)&pW, (void*)&pB, (void*)&a_out, (void*)&np,
                         (void*)&a_bar };
        return hipLaunchCooperativeKernel((void*)vae_stack, dim3(grid), dim3(512),
                                          args, 0, stream);
    };

    // ---------------- encoder (192 blocks: no projection role) --------------
    barinit_k<<<dim3(16), dim3(256), 0, stream>>>(bar);
    hipError_t e1 = coop(192, enc_Wx0, enc_Wh0, enc_Wx12, enc_Wh12,
                         enc_Wx12 + UG, enc_Wh12 + UG,
                         ebr, nullptr, nullptr, nullptr, T + 2);

    // latent head reads encoder h2[t=255] (buf 1): interleaved panel 5
    latent_k<<<dim3(B), dim3(256), 0, stream>>>(h + 5 * (size_t)HBUF,
                                                eps, w_mean, b_mean, w_sigma, b_sigma, lat);
    xcr_k<<<dim3(2048), dim3(256), 0, stream>>>(lat, dec_Wx0, dec_b0, xcr);

    // ---------------- decoder (256 blocks, fused projection) ----------------
    barinit_k<<<dim3(16), dim3(256), 0, stream>>>(bar);
    hipError_t e2 = coop(256, dec_Wx0 + (size_t)L * G4U, dec_Wh0, dec_Wx12, dec_Wh12,
                         dec_Wx12 + UG, dec_Wh12 + UG,
                         ebr + 2 * G4U, xcr, Wt, dec_b, T + 3);

    if (e1 != hipSuccess || e2 != hipSuccess) {
        sentinel_k<<<dim3(1), dim3(64), 0, stream>>>(out, -3.0e6f);
    }
}